// Round 1
// baseline (26520.105 us; speedup 1.0000x reference)
//
#include <hip/hip_runtime.h>

typedef unsigned short u16;
typedef __attribute__((ext_vector_type(8))) short short8;
typedef __attribute__((ext_vector_type(4))) float f32x4;

#define B_  32
#define T_  128
#define N_  196
#define D_  768
#define E_  256
#define H_  512
#define V_  10000
#define G4H 2048

// workspace offsets (bytes), all 256-aligned
#define O_ENCBF  0UL
#define O_WET    9633792UL
#define O_FCWT   10420224UL
#define O_WHBF   20660224UL
#define O_WIHBF  21184512UL
#define O_WHHBF  25378816UL
#define O_KE     27475968UL
#define O_EMBT   33898496UL
#define O_HT     38092800UL
#define O_CT     38158336UL
#define O_HIST   38223872UL
#define O_G1T    42418176UL
#define O_NUMT   42680320UL
#define O_SC     42876928UL
#define O_BARS   42877440UL

__device__ __forceinline__ float b2f(u16 u) {
  union { unsigned i; float f; } c; c.i = ((unsigned)u) << 16; return c.f;
}
__device__ __forceinline__ u16 f2b(float f) {   // RNE f32->bf16
  unsigned u = __float_as_uint(f);
  unsigned r = (u + 0x7fffu + ((u >> 16) & 1u)) >> 16;
  return (u16)r;
}
__device__ __forceinline__ float fast_tanh(float x) {
  float e = __expf(2.f * x);
  return 1.f - 2.f * __builtin_amdgcn_rcpf(e + 1.f);
}
__device__ __forceinline__ float sigm(float x) {
  return __builtin_amdgcn_rcpf(1.f + __expf(-x));
}
__device__ __forceinline__ float wred_sum(float x) {
  #pragma unroll
  for (int o = 32; o; o >>= 1) x += __shfl_xor(x, o, 64);
  return x;
}
__device__ __forceinline__ float wred_max(float x) {
  #pragma unroll
  for (int o = 32; o; o >>= 1) x = fmaxf(x, __shfl_xor(x, o, 64));
  return x;
}

// device-wide barrier: one-shot counter per sync point (zeroed each launch)
__device__ __forceinline__ void gridbar(unsigned* ctr, int nblk) {
  __syncthreads();
  if (threadIdx.x == 0) {
    __threadfence();  // release: make my writes visible device-wide
    __hip_atomic_fetch_add(ctr, 1u, __ATOMIC_RELEASE, __HIP_MEMORY_SCOPE_AGENT);
    while (__hip_atomic_load(ctr, __ATOMIC_RELAXED, __HIP_MEMORY_SCOPE_AGENT) < (unsigned)nblk)
      __builtin_amdgcn_s_sleep(3);
    __threadfence();  // acquire: invalidate stale cached lines
  }
  __syncthreads();
}

// ---------------- small prep kernels ----------------

__global__ void conv_bf(const float* __restrict__ in, u16* __restrict__ out, int n) {
  int i = blockIdx.x * blockDim.x + threadIdx.x;
  int st = gridDim.x * blockDim.x;
  for (; i < n; i += st) out[i] = f2b(in[i]);
}

// out[c][r] = bf16(in[r][c]); in is R x C
__global__ void transpose_bf(const float* __restrict__ in, u16* __restrict__ out, int R, int C) {
  __shared__ float tl[64][65];
  int tid = threadIdx.x;
  int tc0 = blockIdx.x * 64, tr0 = blockIdx.y * 64;
  int cc = tid & 63;
  for (int rr = tid >> 6; rr < 64; rr += 4) {
    int rg = tr0 + rr, cg = tc0 + cc;
    tl[rr][cc] = (rg < R && cg < C) ? in[(size_t)rg * C + cg] : 0.f;
  }
  __syncthreads();
  int rr = tid & 63;
  for (int c2 = tid >> 6; c2 < 64; c2 += 4) {
    int cg = tc0 + c2, rg = tr0 + rr;
    if (cg < C && rg < R) out[(size_t)cg * R + rg] = f2b(tl[rr][c2]);
  }
}

// h0/c0: pooled = mean_n enc[b,n,:]; h0 = tanh(pooled@W2h+b2h) -> hT[h][b]
__global__ __launch_bounds__(512) void init_hc(
    const float* __restrict__ enc, const float* __restrict__ W2h,
    const float* __restrict__ b2h, const float* __restrict__ W2c,
    const float* __restrict__ b2c, float* __restrict__ hT, float* __restrict__ cT)
{
  __shared__ float pool[D_];
  int b = blockIdx.x, tid = threadIdx.x;
  for (int d = tid; d < D_; d += 512) {
    float s = 0.f;
    const float* ep = enc + (size_t)b * N_ * D_ + d;
    for (int n = 0; n < N_; ++n) s += ep[(size_t)n * D_];
    pool[d] = s * (1.f / 196.f);
  }
  __syncthreads();
  float a = b2h[tid], a2 = b2c[tid];
  #pragma unroll 4
  for (int d = 0; d < D_; ++d) {
    float pv = pool[d];
    a  += pv * W2h[d * H_ + tid];
    a2 += pv * W2c[d * H_ + tid];
  }
  hT[tid * 32 + b] = fast_tanh(a);
  cT[tid * 32 + b] = fast_tanh(a2);
}

// embT[t][k][b] = emb_table[x[b][t]][k]
__global__ void embt_k(const int* __restrict__ x, const float* __restrict__ emb,
                       float* __restrict__ embT) {
  __shared__ float le[32 * 257];
  int t = blockIdx.x, tid = threadIdx.x;
  for (int i = tid; i < 32 * 256; i += 256) {
    int b = i >> 8, k = i & 255;
    le[b * 257 + k] = emb[(size_t)x[b * T_ + t] * E_ + k];
  }
  __syncthreads();
  for (int i = tid; i < 32 * 256; i += 256) {
    int k = i >> 5, b = i & 31;
    embT[(size_t)t * (E_ * 32) + k * 32 + b] = le[b * 257 + k];
  }
}

// ---------------- bf16 MFMA GEMM: C[m][n] = sum_k A[m][k]*BT[n][k] (+bias[n]) ----------------
template<int OUT_BF16, int ADD_BIAS>
__global__ __launch_bounds__(256) void gemm_bt(
    const u16* __restrict__ A, const u16* __restrict__ BT,
    void* __restrict__ Cv, const float* __restrict__ bias,
    int M, int N, int K)
{
  __shared__ __align__(16) u16 Al[128][72];
  __shared__ __align__(16) u16 Bl[128][72];
  const int tid = threadIdx.x;
  const int tm0 = blockIdx.y * 128, tn0 = blockIdx.x * 128;
  const int wv = tid >> 6, lane = tid & 63;
  const int wr = wv >> 1, wc = wv & 1;
  f32x4 acc[4][4] = {};
  const int r = tid >> 1, cb = (tid & 1) * 32;
  for (int k0 = 0; k0 < K; k0 += 64) {
    int rm = tm0 + r; if (rm >= M) rm = M - 1;
    int rn = tn0 + r; if (rn >= N) rn = N - 1;
    const u16* gp = A  + (size_t)rm * K + k0 + cb;
    const u16* gq = BT + (size_t)rn * K + k0 + cb;
    #pragma unroll
    for (int u = 0; u < 4; ++u) {
      *(short8*)&Al[r][cb + u * 8] = *(const short8*)(gp + u * 8);
      *(short8*)&Bl[r][cb + u * 8] = *(const short8*)(gq + u * 8);
    }
    __syncthreads();
    #pragma unroll
    for (int kk = 0; kk < 64; kk += 32) {
      short8 af[4], bfv[4];
      #pragma unroll
      for (int i = 0; i < 4; ++i)
        af[i] = *(const short8*)&Al[wr * 64 + i * 16 + (lane & 15)][kk + (lane >> 4) * 8];
      #pragma unroll
      for (int j = 0; j < 4; ++j)
        bfv[j] = *(const short8*)&Bl[wc * 64 + j * 16 + (lane & 15)][kk + (lane >> 4) * 8];
      #pragma unroll
      for (int i = 0; i < 4; ++i)
        #pragma unroll
        for (int j = 0; j < 4; ++j)
          acc[i][j] = __builtin_amdgcn_mfma_f32_16x16x32_bf16(af[i], bfv[j], acc[i][j], 0, 0, 0);
    }
    __syncthreads();
  }
  #pragma unroll
  for (int i = 0; i < 4; ++i) {
    int row0 = tm0 + wr * 64 + i * 16 + (lane >> 4) * 4;
    #pragma unroll
    for (int j = 0; j < 4; ++j) {
      int col = tn0 + wc * 64 + j * 16 + (lane & 15);
      if (col < N) {
        float bs = ADD_BIAS ? bias[col] : 0.f;
        #pragma unroll
        for (int rr2 = 0; rr2 < 4; ++rr2) {
          int row = row0 + rr2;
          if (row < M) {
            float val = acc[i][j][rr2] + bs;
            if (OUT_BF16) ((u16*)Cv)[(size_t)row * N + col] = f2b(val);
            else          ((float*)Cv)[(size_t)row * N + col] = val;
          }
        }
      }
    }
  }
}

// ---------------- persistent recurrent kernel ----------------
// grid = 320 blocks x 512 thr. blocks 0..63: attention (2 per batch, n-halves);
// blocks 64..319: gate-column blocks (8 gate cols each in P1; 2 h-indices in P2).
__global__ __launch_bounds__(512, 4) void recur_kernel(
    const float* __restrict__ enc, const int* __restrict__ mask,
    const u16* __restrict__ Ke, const u16* __restrict__ Wh,
    const float* __restrict__ vvec,
    const u16* __restrict__ Wih, const u16* __restrict__ Whh,
    const float* __restrict__ bih, const float* __restrict__ bhh,
    const float* __restrict__ embT,
    float* hT, float* cT, float* g1T, float* numT, float* sc,
    u16* h_hist, float* out_h, float* out_c, unsigned* bars)
{
  __shared__ float h_l[512];
  __shared__ float hw_l[576];
  __shared__ float s_l[128];
  __shared__ float g_pre[8][32];
  __shared__ float w01[64];

  const int bid = blockIdx.x, tid = threadIdx.x;
  const int lane = tid & 63, wvx = tid >> 6;
  const bool is_attn = (bid < 64);
  const int b_at = bid >> 1, half = bid & 1, n0 = half * 98;
  const int gi = bid - 64;

  float vreg[8];
  if (is_attn) {
    #pragma unroll
    for (int j = 0; j < 8; ++j) vreg[j] = vvec[lane * 8 + j];
  }

  for (int t = 0; t < T_; ++t) {
    // ---------- Phase 1 ----------
    if (is_attn) {
      h_l[tid] = hT[tid * 32 + b_at];
      __syncthreads();
      // hWh[b][tid]
      float acc = 0.f;
      {
        const u16* wp = Wh + tid;
        #pragma unroll 4
        for (int k = 0; k < H_; ++k) acc += h_l[k] * b2f(wp[k * H_]);
      }
      hw_l[tid + (tid >> 3)] = acc;   // padded: idx = 9*(k>>3)... = k + (k>>3)
      __syncthreads();
      // scores for this half's n range
      for (int nn = wvx; nn < 98; nn += 8) {
        int n = n0 + nn;
        const u16* kp = Ke + ((size_t)(b_at * N_ + n)) * H_ + lane * 8;
        short8 kv = *(const short8*)kp;
        float p = 0.f;
        int base = lane * 9;
        #pragma unroll
        for (int j = 0; j < 8; ++j)
          p += vreg[j] * fast_tanh(hw_l[base + j] + b2f((u16)kv[j]));
        p = wred_sum(p);
        if (lane == 0) s_l[nn] = (mask[b_at * N_ + n] == 0) ? -1e9f : p;
      }
      __syncthreads();
      // partial softmax stats over this half
      if (wvx == 0) {
        float m = -3.4e38f;
        for (int nn = lane; nn < 98; nn += 64) m = fmaxf(m, s_l[nn]);
        m = wred_max(m);
        float dsum = 0.f;
        for (int nn = lane; nn < 98; nn += 64) {
          float e = __expf(s_l[nn] - m); s_l[nn] = e; dsum += e;
        }
        dsum = wred_sum(dsum);
        if (lane == 0) { sc[(b_at * 2 + half) * 2] = m; sc[(b_at * 2 + half) * 2 + 1] = dsum; }
      }
      __syncthreads();
      // partial (unnormalized) context numerator -> numT[half][d][b]
      for (int d = tid; d < D_; d += 512) {
        float a = 0.f;
        const float* ep = enc + ((size_t)(b_at * N_ + n0)) * D_ + d;
        for (int nn = 0; nn < 98; ++nn) a += s_l[nn] * ep[(size_t)nn * D_];
        numT[(half * D_ + d) * 32 + b_at] = a;
      }
    } else {
      // g1 = e_t @ Wih[0:256] + h @ Whh + bih + bhh, 8 cols per block
      const int dotid = tid >> 1, p = tid & 1;
      const int bb = dotid & 31, cc = dotid >> 5;
      const int col = gi * 8 + cc;
      float a = 0.f;
      if (p == 0) {
        const float* ep = embT + (size_t)t * (E_ * 32) + bb;
        const u16* wp = Wih + col;
        #pragma unroll 4
        for (int k = 0; k < E_; ++k) a += ep[k * 32] * b2f(wp[(size_t)k * G4H]);
        const float* hp = hT + bb;
        const u16* wh = Whh + col;
        #pragma unroll 4
        for (int k = 0; k < 128; ++k) a += hp[k * 32] * b2f(wh[(size_t)k * G4H]);
      } else {
        const float* hp = hT + bb;
        const u16* wh = Whh + col;
        #pragma unroll 4
        for (int k = 128; k < 512; ++k) a += hp[k * 32] * b2f(wh[(size_t)k * G4H]);
      }
      a += __shfl_xor(a, 1, 64);
      if (p == 0) g1T[col * 32 + bb] = a + bih[col] + bhh[col];
    }
    gridbar(&bars[2 * t], 320);

    // ---------- Phase 2 (gate blocks only) ----------
    if (!is_attn) {
      if (tid < 32) {
        float m0 = sc[tid * 4], d0 = sc[tid * 4 + 1];
        float m1 = sc[tid * 4 + 2], d1 = sc[tid * 4 + 3];
        float M = fmaxf(m0, m1);
        float e0 = __expf(m0 - M), e1 = __expf(m1 - M);
        float rD = 1.f / (d0 * e0 + d1 * e1);
        w01[tid * 2] = e0 * rD; w01[tid * 2 + 1] = e1 * rD;
      }
      __syncthreads();
      const int dotid = tid >> 1, p = tid & 1;
      const int bb = dotid & 31, cc = dotid >> 5;     // cc = q*2+jj
      const int q = cc >> 1, jj = cc & 1;
      const int col = q * H_ + gi * 2 + jj;
      const int dbase = p * 384;
      float a0 = 0.f, a1 = 0.f;
      const float* np0 = numT + dbase * 32 + bb;
      const float* np1 = numT + (D_ + dbase) * 32 + bb;
      const u16* wp = Wih + (size_t)(E_ + dbase) * G4H + col;
      #pragma unroll 4
      for (int d = 0; d < 384; ++d) {
        float w = b2f(wp[(size_t)d * G4H]);
        a0 += np0[d * 32] * w;
        a1 += np1[d * 32] * w;
      }
      float g2 = w01[bb * 2] * a0 + w01[bb * 2 + 1] * a1;
      g2 += __shfl_xor(g2, 1, 64);
      if (p == 0) g_pre[cc][bb] = g2 + g1T[col * 32 + bb];
      __syncthreads();
      if (tid < 64) {
        int bb2 = tid & 31, jj2 = tid >> 5;
        int hidx = gi * 2 + jj2;
        float gI = g_pre[0 + jj2][bb2], gF = g_pre[2 + jj2][bb2];
        float gG = g_pre[4 + jj2][bb2], gO = g_pre[6 + jj2][bb2];
        float co = cT[hidx * 32 + bb2];
        float cn = sigm(gF) * co + sigm(gI) * fast_tanh(gG);
        float hn = sigm(gO) * fast_tanh(cn);
        cT[hidx * 32 + bb2] = cn;
        hT[hidx * 32 + bb2] = hn;
        h_hist[((size_t)bb2 * T_ + t) * H_ + hidx] = f2b(hn);
        if (t == T_ - 1) {
          out_h[bb2 * H_ + hidx] = hn;
          out_c[bb2 * H_ + hidx] = cn;
        }
      }
    }
    gridbar(&bars[2 * t + 1], 320);
  }
}

extern "C" void kernel_launch(void* const* d_in, const int* in_sizes, int n_in,
                              void* d_out, int out_size, void* d_ws, size_t ws_size,
                              hipStream_t stream) {
  const int*   x    = (const int*)d_in[0];
  const float* enc  = (const float*)d_in[1];
  const int*   mask = (const int*)d_in[2];
  const float* emb  = (const float*)d_in[3];
  const float* We   = (const float*)d_in[4];
  const float* Wh   = (const float*)d_in[5];
  const float* v    = (const float*)d_in[6];
  const float* Wih  = (const float*)d_in[7];
  const float* Whh  = (const float*)d_in[8];
  const float* bih  = (const float*)d_in[9];
  const float* bhh  = (const float*)d_in[10];
  const float* fcW  = (const float*)d_in[11];
  const float* fcb  = (const float*)d_in[12];
  const float* W2h  = (const float*)d_in[13];
  const float* b2h  = (const float*)d_in[14];
  const float* W2c  = (const float*)d_in[15];
  const float* b2c  = (const float*)d_in[16];
  float* out = (float*)d_out;

  char* ws = (char*)d_ws;
  u16* enc_bf = (u16*)(ws + O_ENCBF);
  u16* WeT    = (u16*)(ws + O_WET);
  u16* fcWT   = (u16*)(ws + O_FCWT);
  u16* Wh_bf  = (u16*)(ws + O_WHBF);
  u16* Wih_bf = (u16*)(ws + O_WIHBF);
  u16* Whh_bf = (u16*)(ws + O_WHHBF);
  u16* Ke     = (u16*)(ws + O_KE);
  float* embT = (float*)(ws + O_EMBT);
  float* hT   = (float*)(ws + O_HT);
  float* cT   = (float*)(ws + O_CT);
  u16* h_hist = (u16*)(ws + O_HIST);
  float* g1T  = (float*)(ws + O_G1T);
  float* numT = (float*)(ws + O_NUMT);
  float* sc   = (float*)(ws + O_SC);
  unsigned* bars = (unsigned*)(ws + O_BARS);

  hipMemsetAsync(bars, 0, 2048, stream);
  conv_bf<<<1024, 256, 0, stream>>>(enc, enc_bf, B_ * N_ * D_);
  conv_bf<<<256, 256, 0, stream>>>(Wh, Wh_bf, H_ * H_);
  conv_bf<<<1024, 256, 0, stream>>>(Wih, Wih_bf, (E_ + D_) * G4H);
  conv_bf<<<512, 256, 0, stream>>>(Whh, Whh_bf, H_ * G4H);
  transpose_bf<<<dim3(8, 12), 256, 0, stream>>>(We, WeT, D_, H_);
  transpose_bf<<<dim3(157, 8), 256, 0, stream>>>(fcW, fcWT, H_, V_);
  init_hc<<<32, 512, 0, stream>>>(enc, W2h, b2h, W2c, b2c, hT, cT);
  embt_k<<<128, 256, 0, stream>>>(x, emb, embT);
  // Ke = enc @ We  (M=6272, N=512, K=768), bf16 out
  gemm_bt<1, 0><<<dim3(4, 49), 256, 0, stream>>>(enc_bf, WeT, (void*)Ke, nullptr,
                                                 B_ * N_, H_, D_);
  recur_kernel<<<320, 512, 0, stream>>>(enc, mask, Ke, Wh_bf, v, Wih_bf, Whh_bf,
      bih, bhh, embT, hT, cT, g1T, numT, sc, h_hist,
      out + (size_t)B_ * T_ * V_, out + (size_t)B_ * T_ * V_ + B_ * H_, bars);
  // logits = h_hist @ fcW + fcb  (M=4096, N=10000, K=512), f32 out
  gemm_bt<0, 1><<<dim3(79, 32), 256, 0, stream>>>(h_hist, fcWT, (void*)out, fcb,
                                                  B_ * T_, V_, H_);
}

// Round 2
// 13150.322 us; speedup vs baseline: 2.0167x; 2.0167x over previous
//
#include <hip/hip_runtime.h>

typedef unsigned short u16;
typedef __attribute__((ext_vector_type(8))) short short8;
typedef __attribute__((ext_vector_type(4))) float f32x4;
typedef __attribute__((ext_vector_type(4))) unsigned int u32x4;

#define B_  32
#define T_  128
#define N_  196
#define D_  768
#define E_  256
#define H_  512
#define V_  10000
#define G4H 2048
#define NBLK 288

// workspace offsets (bytes), all 256-aligned
#define O_ENCBF 0UL            // 9,633,792   enc bf16 [32][196][768]
#define O_WHT   9633792UL      // 524,288     WhT  [512 col][512 k]
#define O_WHHT  10158080UL     // 2,097,152   WhhT [2048 col][512 k]
#define O_WIHDT 12255232UL     // 3,145,728   WihDT[2048 col][768 d]
#define O_KE    15400960UL     // 6,422,528   Ke bf16 [6272][512]
#define O_GEMB  21823488UL     // 16,777,216  g_emb bf16 [128 t][2048 col][32 b]
#define O_BSUM  38600704UL     // 8,192       bih+bhh
#define O_HT    38608896UL     // 65,536      h f32 [32][512]
#define O_CT    38674432UL     // 65,536      c0 f32 [32][512]
#define O_CTX   38739968UL     // 49,152      ctx bf16 [32][768]
#define O_HIST  38789120UL     // 4,194,304   h_hist bf16 [32*128][512]
#define O_BARS  42983424UL     // 1,024

__device__ __forceinline__ float b2f(u16 u) {
  union { unsigned i; float f; } c; c.i = ((unsigned)u) << 16; return c.f;
}
__device__ __forceinline__ u16 f2b(float f) {   // RNE f32->bf16
  unsigned u = __float_as_uint(f);
  unsigned r = (u + 0x7fffu + ((u >> 16) & 1u)) >> 16;
  return (u16)r;
}
__device__ __forceinline__ float fast_tanh(float x) {
  float e = __expf(2.f * x);
  return 1.f - 2.f * __builtin_amdgcn_rcpf(e + 1.f);
}
__device__ __forceinline__ float sigm(float x) {
  return __builtin_amdgcn_rcpf(1.f + __expf(-x));
}
__device__ __forceinline__ float wred_sum(float x) {
  #pragma unroll
  for (int o = 32; o; o >>= 1) x += __shfl_xor(x, o, 64);
  return x;
}
__device__ __forceinline__ float wred_max(float x) {
  #pragma unroll
  for (int o = 32; o; o >>= 1) x = fmaxf(x, __shfl_xor(x, o, 64));
  return x;
}

// ---- L2-bypass (device-coherent) memory ops: read/write at L3, never cached ----
__device__ __forceinline__ float ld_bypass_f32(const float* p) {
  float v;
  asm volatile("global_load_dword %0, %1, off sc0 sc1\n\ts_waitcnt vmcnt(0)"
               : "=v"(v) : "v"(p) : "memory");
  return v;
}
__device__ __forceinline__ void ld4_bypass(const void* p0, const void* p1,
                                           const void* p2, const void* p3,
                                           u32x4& a, u32x4& b, u32x4& c, u32x4& d) {
  asm volatile(
    "global_load_dwordx4 %0, %4, off sc0 sc1\n\t"
    "global_load_dwordx4 %1, %5, off sc0 sc1\n\t"
    "global_load_dwordx4 %2, %6, off sc0 sc1\n\t"
    "global_load_dwordx4 %3, %7, off sc0 sc1\n\t"
    "s_waitcnt vmcnt(0)"
    : "=v"(a), "=v"(b), "=v"(c), "=v"(d)
    : "v"(p0), "v"(p1), "v"(p2), "v"(p3) : "memory");
}
__device__ __forceinline__ void ld2_bypass(const void* p0, const void* p1,
                                           u32x4& a, u32x4& b) {
  asm volatile(
    "global_load_dwordx4 %0, %2, off sc0 sc1\n\t"
    "global_load_dwordx4 %1, %3, off sc0 sc1\n\t"
    "s_waitcnt vmcnt(0)"
    : "=v"(a), "=v"(b) : "v"(p0), "v"(p1) : "memory");
}
__device__ __forceinline__ void st_bypass_f32(float* p, float v) {
  asm volatile("global_store_dword %0, %1, off sc0 sc1" :: "v"(p), "v"(v) : "memory");
}
__device__ __forceinline__ void st_bypass_u16(u16* p, u16 v) {
  unsigned vv = v;
  asm volatile("global_store_short %0, %1, off sc0 sc1" :: "v"(p), "v"(vv) : "memory");
}

// grid barrier WITHOUT acquire-invalidate: __syncthreads drains each wave's
// vmcnt (bypass stores reached L3); release-add orders; readers use bypass
// loads so no cache can serve stale data -> L2 weight residency preserved.
__device__ __forceinline__ void gridbar(unsigned* ctr, unsigned nblk) {
  __syncthreads();
  if (threadIdx.x == 0) {
    __hip_atomic_fetch_add(ctr, 1u, __ATOMIC_RELEASE, __HIP_MEMORY_SCOPE_AGENT);
    while (__hip_atomic_load(ctr, __ATOMIC_RELAXED, __HIP_MEMORY_SCOPE_AGENT) < nblk)
      __builtin_amdgcn_s_sleep(2);
  }
  __syncthreads();
}

// ---------------- prep kernels ----------------

__global__ void conv_bf(const float* __restrict__ in, u16* __restrict__ out, int n) {
  int i = blockIdx.x * blockDim.x + threadIdx.x;
  int st = gridDim.x * blockDim.x;
  for (; i < n; i += st) out[i] = f2b(in[i]);
}

__global__ void bsum_k(const float* __restrict__ a, const float* __restrict__ b,
                       float* __restrict__ o, int n) {
  int i = blockIdx.x * blockDim.x + threadIdx.x;
  if (i < n) o[i] = a[i] + b[i];
}

// out[c][r] = bf16(in[r][c]); in is R x C
__global__ void transpose_bf(const float* __restrict__ in, u16* __restrict__ out, int R, int C) {
  __shared__ float tl[64][65];
  int tid = threadIdx.x;
  int tc0 = blockIdx.x * 64, tr0 = blockIdx.y * 64;
  int cc = tid & 63;
  for (int rr = tid >> 6; rr < 64; rr += 4) {
    int rg = tr0 + rr, cg = tc0 + cc;
    tl[rr][cc] = (rg < R && cg < C) ? in[(size_t)rg * C + cg] : 0.f;
  }
  __syncthreads();
  int rr = tid & 63;
  for (int c2 = tid >> 6; c2 < 64; c2 += 4) {
    int cg = tc0 + c2, rg = tr0 + rr;
    if (cg < C && rg < R) out[(size_t)cg * R + rg] = f2b(tl[rr][c2]);
  }
}

// h0/c0 into [b][h] layout
__global__ __launch_bounds__(512) void init_hc(
    const float* __restrict__ enc, const float* __restrict__ W2h,
    const float* __restrict__ b2h, const float* __restrict__ W2c,
    const float* __restrict__ b2c, float* __restrict__ hT, float* __restrict__ cT)
{
  __shared__ float pool[D_];
  int b = blockIdx.x, tid = threadIdx.x;
  for (int d = tid; d < D_; d += 512) {
    float s = 0.f;
    const float* ep = enc + (size_t)b * N_ * D_ + d;
    for (int n = 0; n < N_; ++n) s += ep[(size_t)n * D_];
    pool[d] = s * (1.f / 196.f);
  }
  __syncthreads();
  float a = b2h[tid], a2 = b2c[tid];
  #pragma unroll 4
  for (int d = 0; d < D_; ++d) {
    float pv = pool[d];
    a  += pv * W2h[d * H_ + tid];
    a2 += pv * W2c[d * H_ + tid];
  }
  hT[b * H_ + tid] = fast_tanh(a);
  cT[b * H_ + tid] = fast_tanh(a2);
}

// ---------------- MFMA GEMM, B given as f32 K x N row-major (converted in-stage) ----
// AMODE: 0 = A bf16 [M][lda];  1 = A f32 with row gather via xidx (emb table)
// OUTMODE: 0 = f32 row-major; 1 = bf16 row-major; 3 = bf16 scatter [t][col][b]
template<int AMODE, int OUTMODE, int BIAS>
__global__ __launch_bounds__(256) void gemm2(
    const void* __restrict__ Av, const float* __restrict__ Bf,
    const int* __restrict__ xidx, void* __restrict__ Cv,
    const float* __restrict__ bias, int M, int N, int K, int lda)
{
  __shared__ __align__(16) u16 Al[128][72];
  __shared__ __align__(16) u16 Bl[128][72];
  const int tid = threadIdx.x;
  const int tm0 = blockIdx.y * 128, tn0 = blockIdx.x * 128;
  const int wv = tid >> 6, lane = tid & 63;
  const int wr = wv >> 1, wc = wv & 1;
  f32x4 acc[4][4] = {};
  const int r = tid >> 1, cb = (tid & 1) * 32;
  const int bkr = tid >> 5;          // 0..7
  const int bnc = (tid & 31) * 4;    // 0..124
  for (int k0 = 0; k0 < K; k0 += 64) {
    int rm = tm0 + r; if (rm >= M) rm = M - 1;
    if (AMODE == 0) {
      const u16* gp = (const u16*)Av + (size_t)rm * lda + k0 + cb;
      #pragma unroll
      for (int u = 0; u < 4; ++u)
        *(short8*)&Al[r][cb + u * 8] = *(const short8*)(gp + u * 8);
    } else {
      const float* gp = (const float*)Av + (size_t)xidx[rm] * lda + k0 + cb;
      #pragma unroll
      for (int u = 0; u < 4; ++u) {
        f32x4 a0 = *(const f32x4*)(gp + u * 8);
        f32x4 a1 = *(const f32x4*)(gp + u * 8 + 4);
        Al[r][cb + u * 8 + 0] = f2b(a0[0]); Al[r][cb + u * 8 + 1] = f2b(a0[1]);
        Al[r][cb + u * 8 + 2] = f2b(a0[2]); Al[r][cb + u * 8 + 3] = f2b(a0[3]);
        Al[r][cb + u * 8 + 4] = f2b(a1[0]); Al[r][cb + u * 8 + 5] = f2b(a1[1]);
        Al[r][cb + u * 8 + 6] = f2b(a1[2]); Al[r][cb + u * 8 + 7] = f2b(a1[3]);
      }
    }
    {
      int ncc = tn0 + bnc; if (ncc > N - 4) ncc = N - 4;
      #pragma unroll
      for (int u = 0; u < 8; ++u) {
        int kr = bkr + u * 8;
        const float* bp = Bf + (size_t)(k0 + kr) * N + ncc;
        f32x4 bv = *(const f32x4*)bp;
        #pragma unroll
        for (int j = 0; j < 4; ++j) Bl[bnc + j][kr] = f2b(bv[j]);
      }
    }
    __syncthreads();
    #pragma unroll
    for (int kk = 0; kk < 64; kk += 32) {
      short8 af[4], bfv[4];
      #pragma unroll
      for (int i = 0; i < 4; ++i)
        af[i] = *(const short8*)&Al[wr * 64 + i * 16 + (lane & 15)][kk + (lane >> 4) * 8];
      #pragma unroll
      for (int j = 0; j < 4; ++j)
        bfv[j] = *(const short8*)&Bl[wc * 64 + j * 16 + (lane & 15)][kk + (lane >> 4) * 8];
      #pragma unroll
      for (int i = 0; i < 4; ++i)
        #pragma unroll
        for (int j = 0; j < 4; ++j)
          acc[i][j] = __builtin_amdgcn_mfma_f32_16x16x32_bf16(af[i], bfv[j], acc[i][j], 0, 0, 0);
    }
    __syncthreads();
  }
  #pragma unroll
  for (int i = 0; i < 4; ++i) {
    int row0 = tm0 + wr * 64 + i * 16 + (lane >> 4) * 4;
    #pragma unroll
    for (int j = 0; j < 4; ++j) {
      int col = tn0 + wc * 64 + j * 16 + (lane & 15);
      if (col < N) {
        float bs = BIAS ? bias[col] : 0.f;
        #pragma unroll
        for (int rr2 = 0; rr2 < 4; ++rr2) {
          int row = row0 + rr2;
          if (row < M) {
            float val = acc[i][j][rr2] + bs;
            if (OUTMODE == 0) ((float*)Cv)[(size_t)row * N + col] = val;
            else if (OUTMODE == 1) ((u16*)Cv)[(size_t)row * N + col] = f2b(val);
            else {
              int tt = row & 127, bb = row >> 7;
              ((u16*)Cv)[((size_t)tt * G4H + col) * 32 + bb] = f2b(val);
            }
          }
        }
      }
    }
  }
}

// ---------------- persistent recurrent kernel ----------------
// 288 blocks x 512. blocks 0..31: attention (1 per batch); 32..287: gates
// (block gi owns h-indices gi*2, gi*2+1 across all 4 gates = 8 columns).
__global__ __launch_bounds__(512, 4) void recur2(
    const u16* __restrict__ enc_bf, const int* __restrict__ mask,
    const u16* __restrict__ Ke, const u16* __restrict__ WhT,
    const float* __restrict__ vvec, const u16* __restrict__ WhhT,
    const u16* __restrict__ WihDT, const u16* __restrict__ g_emb,
    const float* __restrict__ cT0,
    float* hT, u16* ctxB, u16* h_hist, float* out_h, float* out_c,
    unsigned* bars)
{
  __shared__ union {
    struct {
      float h[512];
      float hw8[512];       // [j][64]
      float sl[256];
      float maskadd[256];
      float part[8][768];
      float rd;
    } at;
    struct { u16 hst[512 * 34]; } g1;      // h staged bf16, [k][b] pad 34
    struct { u32x4 ctx[96 * 33]; } g2;     // ctx staged, [d8][b] pad 33 (16B units)
  } su;
  __shared__ float g1l[8][32];
  __shared__ float gpre[8][32];
  __shared__ float cfl[2][32];

  const int bid = blockIdx.x, tid = threadIdx.x;
  const int lane = tid & 63, wvx = tid >> 6;
  const bool is_attn = bid < 32;
  const int b_at = bid;
  const int gi = bid - 32;
  const int p_ = lane >> 5, bb_ = lane & 31;

  float vreg[8];
  if (is_attn) {
    #pragma unroll
    for (int j = 0; j < 8; ++j) vreg[j] = vvec[lane * 8 + j];
    for (int nn = tid; nn < N_; nn += 512)
      su.at.maskadd[nn] = (mask[b_at * N_ + nn] == 0) ? -1e9f : 0.f;
  } else {
    if (tid < 64) {
      int bb = tid & 31, j2 = tid >> 5;
      cfl[j2][bb] = cT0[bb * H_ + gi * 2 + j2];
    }
  }
  __syncthreads();

  for (int t = 0; t < T_; ++t) {
    // ================= Phase 1 =================
    if (is_attn) {
      float hv = ld_bypass_f32(hT + b_at * H_ + tid);
      su.at.h[tid] = hv;
      __syncthreads();
      float hreg[8];
      #pragma unroll
      for (int j = 0; j < 8; ++j) hreg[j] = su.at.h[lane * 8 + j];
      // hw[col] = h . Wh[:,col]; wave covers 64 cols, lane splits K
      #pragma unroll 2
      for (int c = wvx * 64; c < wvx * 64 + 64; ++c) {
        short8 w = *(const short8*)(WhT + (size_t)c * H_ + lane * 8);
        float a = 0.f;
        #pragma unroll
        for (int j = 0; j < 8; ++j) a += b2f((u16)w[j]) * hreg[j];
        a = wred_sum(a);
        if (lane == 0) su.at.hw8[(c & 7) * 64 + (c >> 3)] = a;
      }
      __syncthreads();
      // scores
      for (int nn = wvx; nn < N_; nn += 8) {
        short8 kv = *(const short8*)(Ke + ((size_t)(b_at * N_ + nn)) * H_ + lane * 8);
        float p = 0.f;
        #pragma unroll
        for (int j = 0; j < 8; ++j)
          p += vreg[j] * fast_tanh(su.at.hw8[j * 64 + lane] + b2f((u16)kv[j]));
        p = wred_sum(p);
        if (lane == 0) su.at.sl[nn] = p + su.at.maskadd[nn];
      }
      __syncthreads();
      // softmax stats (wave 0), exp in place
      if (wvx == 0) {
        float m = -3.4e38f;
        for (int nn = lane; nn < N_; nn += 64) m = fmaxf(m, su.at.sl[nn]);
        m = wred_max(m);
        float s = 0.f;
        for (int nn = lane; nn < N_; nn += 64) {
          float e = __expf(su.at.sl[nn] - m);
          su.at.sl[nn] = e; s += e;
        }
        s = wred_sum(s);
        if (lane == 0) su.at.rd = 1.f / s;
      }
      __syncthreads();
      // context partials (coalesced short8 enc reads)
      float acc0[8] = {0,0,0,0,0,0,0,0}, acc1[8] = {0,0,0,0,0,0,0,0};
      for (int nn = wvx; nn < N_; nn += 8) {
        float al = su.at.sl[nn];
        const u16* ep = enc_bf + ((size_t)(b_at * N_ + nn)) * D_;
        short8 e0 = *(const short8*)(ep + lane * 8);
        #pragma unroll
        for (int j = 0; j < 8; ++j) acc0[j] += al * b2f((u16)e0[j]);
        if (lane < 32) {
          short8 e1 = *(const short8*)(ep + 512 + lane * 8);
          #pragma unroll
          for (int j = 0; j < 8; ++j) acc1[j] += al * b2f((u16)e1[j]);
        }
      }
      {
        f32x4 v0 = {acc0[0], acc0[1], acc0[2], acc0[3]};
        f32x4 v1 = {acc0[4], acc0[5], acc0[6], acc0[7]};
        *(f32x4*)&su.at.part[wvx][lane * 8] = v0;
        *(f32x4*)&su.at.part[wvx][lane * 8 + 4] = v1;
        if (lane < 32) {
          f32x4 v2 = {acc1[0], acc1[1], acc1[2], acc1[3]};
          f32x4 v3 = {acc1[4], acc1[5], acc1[6], acc1[7]};
          *(f32x4*)&su.at.part[wvx][512 + lane * 8] = v2;
          *(f32x4*)&su.at.part[wvx][512 + lane * 8 + 4] = v3;
        }
      }
      __syncthreads();
      float rD = su.at.rd;
      for (int d = tid; d < D_; d += 512) {
        float s = 0.f;
        #pragma unroll
        for (int w = 0; w < 8; ++w) s += su.at.part[w][d];
        st_bypass_u16(ctxB + b_at * D_ + d, f2b(s * rD));
      }
    } else {
      // stage h (f32, device-coherent) -> bf16 LDS [k][b]
      {
        u32x4 v[8];
        ld4_bypass(hT + tid * 4, hT + 2048 + tid * 4, hT + 4096 + tid * 4,
                   hT + 6144 + tid * 4, v[0], v[1], v[2], v[3]);
        ld4_bypass(hT + 8192 + tid * 4, hT + 10240 + tid * 4, hT + 12288 + tid * 4,
                   hT + 14336 + tid * 4, v[4], v[5], v[6], v[7]);
        #pragma unroll
        for (int rr = 0; rr < 8; ++rr) {
          int i = rr * 512 + tid;
          int b0 = i >> 7;
          int h0 = (i * 4) & 511;
          #pragma unroll
          for (int j = 0; j < 4; ++j)
            su.g1.hst[(h0 + j) * 34 + b0] = f2b(__uint_as_float(v[rr][j]));
        }
      }
      __syncthreads();
      const int cc = wvx, q = cc >> 1, jj = cc & 1;
      const int col = q * H_ + gi * 2 + jj;
      float a = 0.f;
      {
        const u16* wp = WhhT + (size_t)col * H_ + p_ * 256;
        #pragma unroll 4
        for (int k8 = 0; k8 < 32; ++k8) {
          short8 w = *(const short8*)(wp + k8 * 8);
          int kb = p_ * 256 + k8 * 8;
          #pragma unroll
          for (int j = 0; j < 8; ++j)
            a += b2f((u16)w[j]) * b2f(su.g1.hst[(kb + j) * 34 + bb_]);
        }
      }
      a += __shfl_xor(a, 32, 64);
      if (lane < 32) {
        float ge = b2f(g_emb[((size_t)t * G4H + col) * 32 + bb_]);
        g1l[cc][bb_] = a + ge;
      }
    }
    gridbar(&bars[2 * t], NBLK);

    // ================= Phase 2 (gate blocks) =================
    if (!is_attn) {
      // stage ctx (bf16, device-coherent) -> LDS [d8][b]
      {
        u32x4 v[6];
        ld4_bypass(ctxB + tid * 8, ctxB + 4096 + tid * 8, ctxB + 8192 + tid * 8,
                   ctxB + 12288 + tid * 8, v[0], v[1], v[2], v[3]);
        ld2_bypass(ctxB + 16384 + tid * 8, ctxB + 20480 + tid * 8, v[4], v[5]);
        #pragma unroll
        for (int rr = 0; rr < 6; ++rr) {
          int c = rr * 512 + tid;
          int b0 = c / 96, d8 = c % 96;
          su.g2.ctx[d8 * 33 + b0] = v[rr];
        }
      }
      __syncthreads();
      const int cc = wvx, q = cc >> 1, jj = cc & 1;
      const int col = q * H_ + gi * 2 + jj;
      float a = 0.f;
      {
        const u16* wp = WihDT + (size_t)col * D_ + p_ * 384;
        #pragma unroll 4
        for (int i = 0; i < 48; ++i) {
          short8 w = *(const short8*)(wp + i * 8);
          short8 cx = *(const short8*)&su.g2.ctx[(p_ * 48 + i) * 33 + bb_];
          #pragma unroll
          for (int j = 0; j < 8; ++j)
            a += b2f((u16)w[j]) * b2f((u16)cx[j]);
        }
      }
      a += __shfl_xor(a, 32, 64);
      if (lane < 32) gpre[cc][bb_] = a + g1l[cc][bb_];
      __syncthreads();
      if (tid < 64) {
        int bb = tid & 31, j2 = tid >> 5;
        int hidx = gi * 2 + j2;
        float gI = gpre[0 + j2][bb], gF = gpre[2 + j2][bb];
        float gG = gpre[4 + j2][bb], gO = gpre[6 + j2][bb];
        float co = cfl[j2][bb];
        float cn = sigm(gF) * co + sigm(gI) * fast_tanh(gG);
        float hn = sigm(gO) * fast_tanh(cn);
        cfl[j2][bb] = cn;
        st_bypass_f32(hT + bb * H_ + hidx, hn);
        st_bypass_u16(h_hist + ((size_t)bb * T_ + t) * H_ + hidx, f2b(hn));
        if (t == T_ - 1) {
          out_h[bb * H_ + hidx] = hn;
          out_c[bb * H_ + hidx] = cn;
        }
      }
    }
    gridbar(&bars[2 * t + 1], NBLK);
  }
}

extern "C" void kernel_launch(void* const* d_in, const int* in_sizes, int n_in,
                              void* d_out, int out_size, void* d_ws, size_t ws_size,
                              hipStream_t stream) {
  const int*   x    = (const int*)d_in[0];
  const float* enc  = (const float*)d_in[1];
  const int*   mask = (const int*)d_in[2];
  const float* emb  = (const float*)d_in[3];
  const float* We   = (const float*)d_in[4];
  const float* Wh   = (const float*)d_in[5];
  const float* v    = (const float*)d_in[6];
  const float* Wih  = (const float*)d_in[7];
  const float* Whh  = (const float*)d_in[8];
  const float* bih  = (const float*)d_in[9];
  const float* bhh  = (const float*)d_in[10];
  const float* fcW  = (const float*)d_in[11];
  const float* fcb  = (const float*)d_in[12];
  const float* W2h  = (const float*)d_in[13];
  const float* b2h  = (const float*)d_in[14];
  const float* W2c  = (const float*)d_in[15];
  const float* b2c  = (const float*)d_in[16];
  float* out = (float*)d_out;

  char* ws = (char*)d_ws;
  u16* enc_bf = (u16*)(ws + O_ENCBF);
  u16* WhT    = (u16*)(ws + O_WHT);
  u16* WhhT   = (u16*)(ws + O_WHHT);
  u16* WihDT  = (u16*)(ws + O_WIHDT);
  u16* Ke     = (u16*)(ws + O_KE);
  u16* g_emb  = (u16*)(ws + O_GEMB);
  float* bsum = (float*)(ws + O_BSUM);
  float* hT   = (float*)(ws + O_HT);
  float* cT   = (float*)(ws + O_CT);
  u16* ctxB   = (u16*)(ws + O_CTX);
  u16* h_hist = (u16*)(ws + O_HIST);
  unsigned* bars = (unsigned*)(ws + O_BARS);

  hipMemsetAsync(bars, 0, 1024, stream);
  conv_bf<<<1024, 256, 0, stream>>>(enc, enc_bf, B_ * N_ * D_);
  transpose_bf<<<dim3(8, 8), 256, 0, stream>>>(Wh, WhT, H_, H_);
  transpose_bf<<<dim3(32, 8), 256, 0, stream>>>(Whh, WhhT, H_, G4H);
  transpose_bf<<<dim3(32, 12), 256, 0, stream>>>(Wih + (size_t)E_ * G4H, WihDT, D_, G4H);
  bsum_k<<<8, 256, 0, stream>>>(bih, bhh, bsum, G4H);
  init_hc<<<32, 512, 0, stream>>>(enc, W2h, b2h, W2c, b2c, hT, cT);
  // Ke = enc_bf @ We   (6272 x 512, K=768) -> bf16 row-major
  gemm2<0, 1, 0><<<dim3(4, 49), 256, 0, stream>>>(enc_bf, We, nullptr, (void*)Ke,
                                                  nullptr, B_ * N_, H_, D_, D_);
  // g_emb[t][col][b] = emb[x] @ Wih[:256] + bih + bhh  (4096 x 2048, K=256)
  gemm2<1, 3, 1><<<dim3(16, 32), 256, 0, stream>>>(emb, Wih, x, (void*)g_emb,
                                                   bsum, B_ * T_, G4H, E_, E_);
  recur2<<<NBLK, 512, 0, stream>>>(enc_bf, mask, Ke, WhT, v, WhhT, WihDT, g_emb,
                                   cT, hT, ctxB, h_hist,
                                   out + (size_t)B_ * T_ * V_,
                                   out + (size_t)B_ * T_ * V_ + B_ * H_, bars);
  // logits = h_hist @ fcW + fcb  (4096 x 10000, K=512) -> f32
  gemm2<0, 0, 1><<<dim3(79, 32), 256, 0, stream>>>(h_hist, fcW, nullptr, (void*)out,
                                                   fcb, B_ * T_, V_, H_, H_);
}

// Round 3
// 11941.231 us; speedup vs baseline: 2.2209x; 1.1013x over previous
//
#include <hip/hip_runtime.h>

typedef unsigned short u16;
typedef __attribute__((ext_vector_type(8))) short short8;
typedef __attribute__((ext_vector_type(4))) float f32x4;
typedef __attribute__((ext_vector_type(4))) unsigned int u32x4;

#define B_  32
#define T_  128
#define N_  196
#define D_  768
#define E_  256
#define H_  512
#define V_  10000
#define G4H 2048
#define NBLK 288

// workspace offsets (bytes), all 256-aligned
#define O_ENCBF 0UL            // 9,633,792   enc bf16 [32][196][768]
#define O_WHT   9633792UL      // 524,288     WhT  [512 col][512 k]
#define O_WHHT  10158080UL     // 2,097,152   WhhT [2048 col][512 k]
#define O_WIHDT 12255232UL     // 3,145,728   WihDT[2048 col][768 d]
#define O_KE    15400960UL     // 6,422,528   Ke bf16 [6272][512]
#define O_GEMB  21823488UL     // 16,777,216  g_emb bf16 [128 t][2048 col][32 b]
#define O_BSUM  38600704UL     // 8,192       bih+bhh
#define O_HT    38608896UL     // 65,536      h f32 [32][512]
#define O_CT    38674432UL     // 65,536      c0 f32 [32][512]
#define O_CTX   38739968UL     // 49,152      ctx bf16 [32][768]
#define O_HIST  38789120UL     // 4,194,304   h_hist bf16 [32*128][512]
#define O_BARS  42983424UL     // 1,024

__device__ __forceinline__ float b2f(u16 u) {
  union { unsigned i; float f; } c; c.i = ((unsigned)u) << 16; return c.f;
}
__device__ __forceinline__ u16 f2b(float f) {   // RNE f32->bf16
  unsigned u = __float_as_uint(f);
  unsigned r = (u + 0x7fffu + ((u >> 16) & 1u)) >> 16;
  return (u16)r;
}
__device__ __forceinline__ float fast_tanh(float x) {
  float e = __expf(2.f * x);
  return 1.f - 2.f * __builtin_amdgcn_rcpf(e + 1.f);
}
__device__ __forceinline__ float sigm(float x) {
  return __builtin_amdgcn_rcpf(1.f + __expf(-x));
}
__device__ __forceinline__ float wred_sum(float x) {
  #pragma unroll
  for (int o = 32; o; o >>= 1) x += __shfl_xor(x, o, 64);
  return x;
}
__device__ __forceinline__ float wred_max(float x) {
  #pragma unroll
  for (int o = 32; o; o >>= 1) x = fmaxf(x, __shfl_xor(x, o, 64));
  return x;
}

// ---- L2-bypass (device-coherent) memory ops: read/write at L3, never cached ----
__device__ __forceinline__ float ld_bypass_f32(const float* p) {
  float v;
  asm volatile("global_load_dword %0, %1, off sc0 sc1\n\ts_waitcnt vmcnt(0)"
               : "=v"(v) : "v"(p) : "memory");
  return v;
}
__device__ __forceinline__ void ld4_bypass(const void* p0, const void* p1,
                                           const void* p2, const void* p3,
                                           u32x4& a, u32x4& b, u32x4& c, u32x4& d) {
  asm volatile(
    "global_load_dwordx4 %0, %4, off sc0 sc1\n\t"
    "global_load_dwordx4 %1, %5, off sc0 sc1\n\t"
    "global_load_dwordx4 %2, %6, off sc0 sc1\n\t"
    "global_load_dwordx4 %3, %7, off sc0 sc1\n\t"
    "s_waitcnt vmcnt(0)"
    : "=v"(a), "=v"(b), "=v"(c), "=v"(d)
    : "v"(p0), "v"(p1), "v"(p2), "v"(p3) : "memory");
}
__device__ __forceinline__ void ld2_bypass(const void* p0, const void* p1,
                                           u32x4& a, u32x4& b) {
  asm volatile(
    "global_load_dwordx4 %0, %2, off sc0 sc1\n\t"
    "global_load_dwordx4 %1, %3, off sc0 sc1\n\t"
    "s_waitcnt vmcnt(0)"
    : "=v"(a), "=v"(b) : "v"(p0), "v"(p1) : "memory");
}
__device__ __forceinline__ void st_bypass_f32(float* p, float v) {
  asm volatile("global_store_dword %0, %1, off sc0 sc1" :: "v"(p), "v"(v) : "memory");
}
__device__ __forceinline__ void st_bypass_u16(u16* p, u16 v) {
  unsigned vv = v;
  asm volatile("global_store_short %0, %1, off sc0 sc1" :: "v"(p), "v"(vv) : "memory");
}

// grid barrier, fully RELAXED protocol:
//  - every wave's __syncthreads drains its vmcnt -> all sc0sc1 bypass stores
//    are acked at the coherence point (L3) before any thread arrives
//  - thread 0 then does a RELAXED agent-scope add (no buffer_wbl2, no inv!)
//  - pollers use RELAXED agent loads (uncached); data reads after the barrier
//    are bypass loads, so no cache can serve stale data.
// This keeps L2 weight residency AND avoids per-barrier L2 writeback storms.
__device__ __forceinline__ void gridbar(unsigned* ctr, unsigned nblk) {
  __syncthreads();
  if (threadIdx.x == 0) {
    asm volatile("s_waitcnt vmcnt(0) lgkmcnt(0)" ::: "memory");
    __hip_atomic_fetch_add(ctr, 1u, __ATOMIC_RELAXED, __HIP_MEMORY_SCOPE_AGENT);
    while (__hip_atomic_load(ctr, __ATOMIC_RELAXED, __HIP_MEMORY_SCOPE_AGENT) < nblk)
      __builtin_amdgcn_s_sleep(1);
  }
  __syncthreads();
}

// ---------------- prep kernels ----------------

__global__ void conv_bf(const float* __restrict__ in, u16* __restrict__ out, int n) {
  int i = blockIdx.x * blockDim.x + threadIdx.x;
  int st = gridDim.x * blockDim.x;
  for (; i < n; i += st) out[i] = f2b(in[i]);
}

__global__ void bsum_k(const float* __restrict__ a, const float* __restrict__ b,
                       float* __restrict__ o, int n) {
  int i = blockIdx.x * blockDim.x + threadIdx.x;
  if (i < n) o[i] = a[i] + b[i];
}

// out[c][r] = bf16(in[r][c]); in is R x C
__global__ void transpose_bf(const float* __restrict__ in, u16* __restrict__ out, int R, int C) {
  __shared__ float tl[64][65];
  int tid = threadIdx.x;
  int tc0 = blockIdx.x * 64, tr0 = blockIdx.y * 64;
  int cc = tid & 63;
  for (int rr = tid >> 6; rr < 64; rr += 4) {
    int rg = tr0 + rr, cg = tc0 + cc;
    tl[rr][cc] = (rg < R && cg < C) ? in[(size_t)rg * C + cg] : 0.f;
  }
  __syncthreads();
  int rr = tid & 63;
  for (int c2 = tid >> 6; c2 < 64; c2 += 4) {
    int cg = tc0 + c2, rg = tr0 + rr;
    if (cg < C && rg < R) out[(size_t)cg * R + rg] = f2b(tl[rr][c2]);
  }
}

// h0/c0 into [b][h] layout
__global__ __launch_bounds__(512) void init_hc(
    const float* __restrict__ enc, const float* __restrict__ W2h,
    const float* __restrict__ b2h, const float* __restrict__ W2c,
    const float* __restrict__ b2c, float* __restrict__ hT, float* __restrict__ cT)
{
  __shared__ float pool[D_];
  int b = blockIdx.x, tid = threadIdx.x;
  for (int d = tid; d < D_; d += 512) {
    float s = 0.f;
    const float* ep = enc + (size_t)b * N_ * D_ + d;
    for (int n = 0; n < N_; ++n) s += ep[(size_t)n * D_];
    pool[d] = s * (1.f / 196.f);
  }
  __syncthreads();
  float a = b2h[tid], a2 = b2c[tid];
  #pragma unroll 4
  for (int d = 0; d < D_; ++d) {
    float pv = pool[d];
    a  += pv * W2h[d * H_ + tid];
    a2 += pv * W2c[d * H_ + tid];
  }
  hT[b * H_ + tid] = fast_tanh(a);
  cT[b * H_ + tid] = fast_tanh(a2);
}

// ---------------- MFMA GEMM, B given as f32 K x N row-major (converted in-stage) ----
// AMODE: 0 = A bf16 [M][lda];  1 = A f32 with row gather via xidx (emb table)
// OUTMODE: 0 = f32 row-major; 1 = bf16 row-major; 3 = bf16 scatter [t][col][b]
template<int AMODE, int OUTMODE, int BIAS>
__global__ __launch_bounds__(256) void gemm2(
    const void* __restrict__ Av, const float* __restrict__ Bf,
    const int* __restrict__ xidx, void* __restrict__ Cv,
    const float* __restrict__ bias, int M, int N, int K, int lda)
{
  __shared__ __align__(16) u16 Al[128][72];
  __shared__ __align__(16) u16 Bl[128][72];
  const int tid = threadIdx.x;
  const int tm0 = blockIdx.y * 128, tn0 = blockIdx.x * 128;
  const int wv = tid >> 6, lane = tid & 63;
  const int wr = wv >> 1, wc = wv & 1;
  f32x4 acc[4][4] = {};
  const int r = tid >> 1, cb = (tid & 1) * 32;
  const int bkr = tid >> 5;          // 0..7
  const int bnc = (tid & 31) * 4;    // 0..124
  for (int k0 = 0; k0 < K; k0 += 64) {
    int rm = tm0 + r; if (rm >= M) rm = M - 1;
    if (AMODE == 0) {
      const u16* gp = (const u16*)Av + (size_t)rm * lda + k0 + cb;
      #pragma unroll
      for (int u = 0; u < 4; ++u)
        *(short8*)&Al[r][cb + u * 8] = *(const short8*)(gp + u * 8);
    } else {
      const float* gp = (const float*)Av + (size_t)xidx[rm] * lda + k0 + cb;
      #pragma unroll
      for (int u = 0; u < 4; ++u) {
        f32x4 a0 = *(const f32x4*)(gp + u * 8);
        f32x4 a1 = *(const f32x4*)(gp + u * 8 + 4);
        Al[r][cb + u * 8 + 0] = f2b(a0[0]); Al[r][cb + u * 8 + 1] = f2b(a0[1]);
        Al[r][cb + u * 8 + 2] = f2b(a0[2]); Al[r][cb + u * 8 + 3] = f2b(a0[3]);
        Al[r][cb + u * 8 + 4] = f2b(a1[0]); Al[r][cb + u * 8 + 5] = f2b(a1[1]);
        Al[r][cb + u * 8 + 6] = f2b(a1[2]); Al[r][cb + u * 8 + 7] = f2b(a1[3]);
      }
    }
    {
      int ncc = tn0 + bnc; if (ncc > N - 4) ncc = N - 4;
      #pragma unroll
      for (int u = 0; u < 8; ++u) {
        int kr = bkr + u * 8;
        const float* bp = Bf + (size_t)(k0 + kr) * N + ncc;
        f32x4 bv = *(const f32x4*)bp;
        #pragma unroll
        for (int j = 0; j < 4; ++j) Bl[bnc + j][kr] = f2b(bv[j]);
      }
    }
    __syncthreads();
    #pragma unroll
    for (int kk = 0; kk < 64; kk += 32) {
      short8 af[4], bfv[4];
      #pragma unroll
      for (int i = 0; i < 4; ++i)
        af[i] = *(const short8*)&Al[wr * 64 + i * 16 + (lane & 15)][kk + (lane >> 4) * 8];
      #pragma unroll
      for (int j = 0; j < 4; ++j)
        bfv[j] = *(const short8*)&Bl[wc * 64 + j * 16 + (lane & 15)][kk + (lane >> 4) * 8];
      #pragma unroll
      for (int i = 0; i < 4; ++i)
        #pragma unroll
        for (int j = 0; j < 4; ++j)
          acc[i][j] = __builtin_amdgcn_mfma_f32_16x16x32_bf16(af[i], bfv[j], acc[i][j], 0, 0, 0);
    }
    __syncthreads();
  }
  #pragma unroll
  for (int i = 0; i < 4; ++i) {
    int row0 = tm0 + wr * 64 + i * 16 + (lane >> 4) * 4;
    #pragma unroll
    for (int j = 0; j < 4; ++j) {
      int col = tn0 + wc * 64 + j * 16 + (lane & 15);
      if (col < N) {
        float bs = BIAS ? bias[col] : 0.f;
        #pragma unroll
        for (int rr2 = 0; rr2 < 4; ++rr2) {
          int row = row0 + rr2;
          if (row < M) {
            float val = acc[i][j][rr2] + bs;
            if (OUTMODE == 0) ((float*)Cv)[(size_t)row * N + col] = val;
            else if (OUTMODE == 1) ((u16*)Cv)[(size_t)row * N + col] = f2b(val);
            else {
              int tt = row & 127, bb = row >> 7;
              ((u16*)Cv)[((size_t)tt * G4H + col) * 32 + bb] = f2b(val);
            }
          }
        }
      }
    }
  }
}

// ---------------- persistent recurrent kernel ----------------
// 288 blocks x 512. blocks 0..31: attention (1 per batch); 32..287: gates
// (block gi owns h-indices gi*2, gi*2+1 across all 4 gates = 8 columns).
__global__ __launch_bounds__(512, 4) void recur2(
    const u16* __restrict__ enc_bf, const int* __restrict__ mask,
    const u16* __restrict__ Ke, const u16* __restrict__ WhT,
    const float* __restrict__ vvec, const u16* __restrict__ WhhT,
    const u16* __restrict__ WihDT, const u16* __restrict__ g_emb,
    const float* __restrict__ cT0,
    float* hT, u16* ctxB, u16* h_hist, float* out_h, float* out_c,
    unsigned* bars)
{
  __shared__ union {
    struct {
      float h[512];
      float hw8[512];       // [j][64]
      float sl[256];
      float maskadd[256];
      float part[8][768];
      float rd;
    } at;
    struct { u16 hst[512 * 34]; } g1;      // h staged bf16, [k][b] pad 34
    struct { u32x4 ctx[96 * 33]; } g2;     // ctx staged, [d8][b] pad 33 (16B units)
  } su;
  __shared__ float g1l[8][32];
  __shared__ float gpre[8][32];
  __shared__ float cfl[2][32];

  const int bid = blockIdx.x, tid = threadIdx.x;
  const int lane = tid & 63, wvx = tid >> 6;
  const bool is_attn = bid < 32;
  const int b_at = bid;
  const int gi = bid - 32;
  const int p_ = lane >> 5, bb_ = lane & 31;

  float vreg[8];
  if (is_attn) {
    #pragma unroll
    for (int j = 0; j < 8; ++j) vreg[j] = vvec[lane * 8 + j];
    for (int nn = tid; nn < N_; nn += 512)
      su.at.maskadd[nn] = (mask[b_at * N_ + nn] == 0) ? -1e9f : 0.f;
  } else {
    if (tid < 64) {
      int bb = tid & 31, j2 = tid >> 5;
      cfl[j2][bb] = cT0[bb * H_ + gi * 2 + j2];
    }
  }
  __syncthreads();

  for (int t = 0; t < T_; ++t) {
    // ================= Phase 1 =================
    if (is_attn) {
      float hv = ld_bypass_f32(hT + b_at * H_ + tid);
      su.at.h[tid] = hv;
      __syncthreads();
      float hreg[8];
      #pragma unroll
      for (int j = 0; j < 8; ++j) hreg[j] = su.at.h[lane * 8 + j];
      // hw[col] = h . Wh[:,col]; wave covers 64 cols, lane splits K
      #pragma unroll 2
      for (int c = wvx * 64; c < wvx * 64 + 64; ++c) {
        short8 w = *(const short8*)(WhT + (size_t)c * H_ + lane * 8);
        float a = 0.f;
        #pragma unroll
        for (int j = 0; j < 8; ++j) a += b2f((u16)w[j]) * hreg[j];
        a = wred_sum(a);
        if (lane == 0) su.at.hw8[(c & 7) * 64 + (c >> 3)] = a;
      }
      __syncthreads();
      // scores
      for (int nn = wvx; nn < N_; nn += 8) {
        short8 kv = *(const short8*)(Ke + ((size_t)(b_at * N_ + nn)) * H_ + lane * 8);
        float p = 0.f;
        #pragma unroll
        for (int j = 0; j < 8; ++j)
          p += vreg[j] * fast_tanh(su.at.hw8[j * 64 + lane] + b2f((u16)kv[j]));
        p = wred_sum(p);
        if (lane == 0) su.at.sl[nn] = p + su.at.maskadd[nn];
      }
      __syncthreads();
      // softmax stats (wave 0), exp in place
      if (wvx == 0) {
        float m = -3.4e38f;
        for (int nn = lane; nn < N_; nn += 64) m = fmaxf(m, su.at.sl[nn]);
        m = wred_max(m);
        float s = 0.f;
        for (int nn = lane; nn < N_; nn += 64) {
          float e = __expf(su.at.sl[nn] - m);
          su.at.sl[nn] = e; s += e;
        }
        s = wred_sum(s);
        if (lane == 0) su.at.rd = 1.f / s;
      }
      __syncthreads();
      // context partials (coalesced short8 enc reads)
      float acc0[8] = {0,0,0,0,0,0,0,0}, acc1[8] = {0,0,0,0,0,0,0,0};
      for (int nn = wvx; nn < N_; nn += 8) {
        float al = su.at.sl[nn];
        const u16* ep = enc_bf + ((size_t)(b_at * N_ + nn)) * D_;
        short8 e0 = *(const short8*)(ep + lane * 8);
        #pragma unroll
        for (int j = 0; j < 8; ++j) acc0[j] += al * b2f((u16)e0[j]);
        if (lane < 32) {
          short8 e1 = *(const short8*)(ep + 512 + lane * 8);
          #pragma unroll
          for (int j = 0; j < 8; ++j) acc1[j] += al * b2f((u16)e1[j]);
        }
      }
      {
        f32x4 v0 = {acc0[0], acc0[1], acc0[2], acc0[3]};
        f32x4 v1 = {acc0[4], acc0[5], acc0[6], acc0[7]};
        *(f32x4*)&su.at.part[wvx][lane * 8] = v0;
        *(f32x4*)&su.at.part[wvx][lane * 8 + 4] = v1;
        if (lane < 32) {
          f32x4 v2 = {acc1[0], acc1[1], acc1[2], acc1[3]};
          f32x4 v3 = {acc1[4], acc1[5], acc1[6], acc1[7]};
          *(f32x4*)&su.at.part[wvx][512 + lane * 8] = v2;
          *(f32x4*)&su.at.part[wvx][512 + lane * 8 + 4] = v3;
        }
      }
      __syncthreads();
      float rD = su.at.rd;
      for (int d = tid; d < D_; d += 512) {
        float s = 0.f;
        #pragma unroll
        for (int w = 0; w < 8; ++w) s += su.at.part[w][d];
        st_bypass_u16(ctxB + b_at * D_ + d, f2b(s * rD));
      }
    } else {
      // stage h (f32, device-coherent) -> bf16 LDS [k][b]
      {
        u32x4 v[8];
        ld4_bypass(hT + tid * 4, hT + 2048 + tid * 4, hT + 4096 + tid * 4,
                   hT + 6144 + tid * 4, v[0], v[1], v[2], v[3]);
        ld4_bypass(hT + 8192 + tid * 4, hT + 10240 + tid * 4, hT + 12288 + tid * 4,
                   hT + 14336 + tid * 4, v[4], v[5], v[6], v[7]);
        #pragma unroll
        for (int rr = 0; rr < 8; ++rr) {
          int i = rr * 512 + tid;
          int b0 = i >> 7;
          int h0 = (i * 4) & 511;
          #pragma unroll
          for (int j = 0; j < 4; ++j)
            su.g1.hst[(h0 + j) * 34 + b0] = f2b(__uint_as_float(v[rr][j]));
        }
      }
      __syncthreads();
      const int cc = wvx, q = cc >> 1, jj = cc & 1;
      const int col = q * H_ + gi * 2 + jj;
      float a = 0.f;
      {
        const u16* wp = WhhT + (size_t)col * H_ + p_ * 256;
        #pragma unroll 4
        for (int k8 = 0; k8 < 32; ++k8) {
          short8 w = *(const short8*)(wp + k8 * 8);
          int kb = p_ * 256 + k8 * 8;
          #pragma unroll
          for (int j = 0; j < 8; ++j)
            a += b2f((u16)w[j]) * b2f(su.g1.hst[(kb + j) * 34 + bb_]);
        }
      }
      a += __shfl_xor(a, 32, 64);
      if (lane < 32) {
        float ge = b2f(g_emb[((size_t)t * G4H + col) * 32 + bb_]);
        g1l[cc][bb_] = a + ge;
      }
    }
    gridbar(&bars[2 * t], NBLK);

    // ================= Phase 2 (gate blocks) =================
    if (!is_attn) {
      // stage ctx (bf16, device-coherent) -> LDS [d8][b]
      {
        u32x4 v[6];
        ld4_bypass(ctxB + tid * 8, ctxB + 4096 + tid * 8, ctxB + 8192 + tid * 8,
                   ctxB + 12288 + tid * 8, v[0], v[1], v[2], v[3]);
        ld2_bypass(ctxB + 16384 + tid * 8, ctxB + 20480 + tid * 8, v[4], v[5]);
        #pragma unroll
        for (int rr = 0; rr < 6; ++rr) {
          int c = rr * 512 + tid;
          int b0 = c / 96, d8 = c % 96;
          su.g2.ctx[d8 * 33 + b0] = v[rr];
        }
      }
      __syncthreads();
      const int cc = wvx, q = cc >> 1, jj = cc & 1;
      const int col = q * H_ + gi * 2 + jj;
      float a = 0.f;
      {
        const u16* wp = WihDT + (size_t)col * D_ + p_ * 384;
        #pragma unroll 4
        for (int i = 0; i < 48; ++i) {
          short8 w = *(const short8*)(wp + i * 8);
          short8 cx = *(const short8*)&su.g2.ctx[(p_ * 48 + i) * 33 + bb_];
          #pragma unroll
          for (int j = 0; j < 8; ++j)
            a += b2f((u16)w[j]) * b2f((u16)cx[j]);
        }
      }
      a += __shfl_xor(a, 32, 64);
      if (lane < 32) gpre[cc][bb_] = a + g1l[cc][bb_];
      __syncthreads();
      if (tid < 64) {
        int bb = tid & 31, j2 = tid >> 5;
        int hidx = gi * 2 + j2;
        float gI = gpre[0 + j2][bb], gF = gpre[2 + j2][bb];
        float gG = gpre[4 + j2][bb], gO = gpre[6 + j2][bb];
        float co = cfl[j2][bb];
        float cn = sigm(gF) * co + sigm(gI) * fast_tanh(gG);
        float hn = sigm(gO) * fast_tanh(cn);
        cfl[j2][bb] = cn;
        st_bypass_f32(hT + bb * H_ + hidx, hn);
        st_bypass_u16(h_hist + ((size_t)bb * T_ + t) * H_ + hidx, f2b(hn));
        if (t == T_ - 1) {
          out_h[bb * H_ + hidx] = hn;
          out_c[bb * H_ + hidx] = cn;
        }
      }
    }
    gridbar(&bars[2 * t + 1], NBLK);
  }
}

extern "C" void kernel_launch(void* const* d_in, const int* in_sizes, int n_in,
                              void* d_out, int out_size, void* d_ws, size_t ws_size,
                              hipStream_t stream) {
  const int*   x    = (const int*)d_in[0];
  const float* enc  = (const float*)d_in[1];
  const int*   mask = (const int*)d_in[2];
  const float* emb  = (const float*)d_in[3];
  const float* We   = (const float*)d_in[4];
  const float* Wh   = (const float*)d_in[5];
  const float* v    = (const float*)d_in[6];
  const float* Wih  = (const float*)d_in[7];
  const float* Whh  = (const float*)d_in[8];
  const float* bih  = (const float*)d_in[9];
  const float* bhh  = (const float*)d_in[10];
  const float* fcW  = (const float*)d_in[11];
  const float* fcb  = (const float*)d_in[12];
  const float* W2h  = (const float*)d_in[13];
  const float* b2h  = (const float*)d_in[14];
  const float* W2c  = (const float*)d_in[15];
  const float* b2c  = (const float*)d_in[16];
  float* out = (float*)d_out;

  char* ws = (char*)d_ws;
  u16* enc_bf = (u16*)(ws + O_ENCBF);
  u16* WhT    = (u16*)(ws + O_WHT);
  u16* WhhT   = (u16*)(ws + O_WHHT);
  u16* WihDT  = (u16*)(ws + O_WIHDT);
  u16* Ke     = (u16*)(ws + O_KE);
  u16* g_emb  = (u16*)(ws + O_GEMB);
  float* bsum = (float*)(ws + O_BSUM);
  float* hT   = (float*)(ws + O_HT);
  float* cT   = (float*)(ws + O_CT);
  u16* ctxB   = (u16*)(ws + O_CTX);
  u16* h_hist = (u16*)(ws + O_HIST);
  unsigned* bars = (unsigned*)(ws + O_BARS);

  hipMemsetAsync(bars, 0, 1024, stream);
  conv_bf<<<1024, 256, 0, stream>>>(enc, enc_bf, B_ * N_ * D_);
  transpose_bf<<<dim3(8, 8), 256, 0, stream>>>(Wh, WhT, H_, H_);
  transpose_bf<<<dim3(32, 8), 256, 0, stream>>>(Whh, WhhT, H_, G4H);
  transpose_bf<<<dim3(32, 12), 256, 0, stream>>>(Wih + (size_t)E_ * G4H, WihDT, D_, G4H);
  bsum_k<<<8, 256, 0, stream>>>(bih, bhh, bsum, G4H);
  init_hc<<<32, 512, 0, stream>>>(enc, W2h, b2h, W2c, b2c, hT, cT);
  // Ke = enc_bf @ We   (6272 x 512, K=768) -> bf16 row-major
  gemm2<0, 1, 0><<<dim3(4, 49), 256, 0, stream>>>(enc_bf, We, nullptr, (void*)Ke,
                                                  nullptr, B_ * N_, H_, D_, D_);
  // g_emb[t][col][b] = emb[x] @ Wih[:256] + bih + bhh  (4096 x 2048, K=256)
  gemm2<1, 3, 1><<<dim3(16, 32), 256, 0, stream>>>(emb, Wih, x, (void*)g_emb,
                                                   bsum, B_ * T_, G4H, E_, E_);
  recur2<<<NBLK, 512, 0, stream>>>(enc_bf, mask, Ke, WhT, v, WhhT, WihDT, g_emb,
                                   cT, hT, ctxB, h_hist,
                                   out + (size_t)B_ * T_ * V_,
                                   out + (size_t)B_ * T_ * V_ + B_ * H_, bars);
  // logits = h_hist @ fcW + fcb  (4096 x 10000, K=512) -> f32
  gemm2<0, 0, 1><<<dim3(79, 32), 256, 0, stream>>>(h_hist, fcW, nullptr, (void*)out,
                                                   fcb, B_ * T_, V_, H_, H_);
}

// Round 5
// 8269.321 us; speedup vs baseline: 3.2070x; 1.4440x over previous
//
#include <hip/hip_runtime.h>

typedef unsigned short u16;
typedef __attribute__((ext_vector_type(8))) short short8;
typedef __attribute__((ext_vector_type(4))) float f32x4;
typedef __attribute__((ext_vector_type(4))) unsigned int u32x4;

#define B_  32
#define T_  128
#define N_  196
#define D_  768
#define E_  256
#define H_  512
#define V_  10000
#define G4H 2048
#define NATT 32
#define NGATE 128
#define NBLK 160

// workspace offsets (bytes), all 256-aligned
#define O_ENCBF 0UL            // 9,633,792   enc bf16 [32][196][768]
#define O_WHBFR 9633792UL      // 524,288     Wh bf16 row-major [k][col]
#define O_WHHT  10158080UL     // 2,097,152   WhhT [2048 col][512 k]
#define O_WIHDT 12255232UL     // 3,145,728   WihDT[2048 col][768 d]
#define O_KE    15400960UL     // 6,422,528   Ke bf16 [6272][512]
#define O_GEMB  21823488UL     // 16,777,216  g_emb bf16 [128 t][2048 col][32 b]
#define O_BSUM  38600704UL     // 8,192       bih+bhh
#define O_HT    38608896UL     // 65,536      h f32 [32][512]
#define O_CT    38674432UL     // 65,536      c0 f32 [32][512]
#define O_CTX   38739968UL     // 49,152      ctx bf16 [32][768]
#define O_HIST  38789120UL     // 4,194,304   h_hist bf16 [32*128][512]
#define O_BARS  42983424UL     // 2,048       16 barrier lines x 128B
#define O_HT2   42985472UL     // 32,768      h bf16 [32][512]

__device__ __forceinline__ float b2f(u16 u) {
  union { unsigned i; float f; } c; c.i = ((unsigned)u) << 16; return c.f;
}
__device__ __forceinline__ u16 f2b(float f) {   // RNE f32->bf16
  unsigned u = __float_as_uint(f);
  unsigned r = (u + 0x7fffu + ((u >> 16) & 1u)) >> 16;
  return (u16)r;
}
__device__ __forceinline__ float fast_tanh(float x) {
  float e = __expf(2.f * x);
  return 1.f - 2.f * __builtin_amdgcn_rcpf(e + 1.f);
}
__device__ __forceinline__ float sigm(float x) {
  return __builtin_amdgcn_rcpf(1.f + __expf(-x));
}
__device__ __forceinline__ float wred_sum(float x) {
  #pragma unroll
  for (int o = 32; o; o >>= 1) x += __shfl_xor(x, o, 64);
  return x;
}
__device__ __forceinline__ float wred_max(float x) {
  #pragma unroll
  for (int o = 32; o; o >>= 1) x = fmaxf(x, __shfl_xor(x, o, 64));
  return x;
}

// ---- L2-bypass (device-coherent) ops: read/write at the coherence point ----
__device__ __forceinline__ float ld_bypass_f32(const float* p) {
  float v;
  asm volatile("global_load_dword %0, %1, off sc0 sc1\n\ts_waitcnt vmcnt(0)"
               : "=v"(v) : "v"(p) : "memory");
  return v;
}
__device__ __forceinline__ void ld4_bypass(const void* p0, const void* p1,
                                           const void* p2, const void* p3,
                                           u32x4& a, u32x4& b, u32x4& c, u32x4& d) {
  asm volatile(
    "global_load_dwordx4 %0, %4, off sc0 sc1\n\t"
    "global_load_dwordx4 %1, %5, off sc0 sc1\n\t"
    "global_load_dwordx4 %2, %6, off sc0 sc1\n\t"
    "global_load_dwordx4 %3, %7, off sc0 sc1\n\t"
    "s_waitcnt vmcnt(0)"
    : "=&v"(a), "=&v"(b), "=&v"(c), "=&v"(d)
    : "v"(p0), "v"(p1), "v"(p2), "v"(p3) : "memory");
}
__device__ __forceinline__ void ld6_bypass(const void* p0, const void* p1,
    const void* p2, const void* p3, const void* p4, const void* p5,
    u32x4& a, u32x4& b, u32x4& c, u32x4& d, u32x4& e, u32x4& f) {
  asm volatile(
    "global_load_dwordx4 %0, %6, off sc0 sc1\n\t"
    "global_load_dwordx4 %1, %7, off sc0 sc1\n\t"
    "global_load_dwordx4 %2, %8, off sc0 sc1\n\t"
    "global_load_dwordx4 %3, %9, off sc0 sc1\n\t"
    "global_load_dwordx4 %4, %10, off sc0 sc1\n\t"
    "global_load_dwordx4 %5, %11, off sc0 sc1\n\t"
    "s_waitcnt vmcnt(0)"
    : "=&v"(a), "=&v"(b), "=&v"(c), "=&v"(d), "=&v"(e), "=&v"(f)
    : "v"(p0), "v"(p1), "v"(p2), "v"(p3), "v"(p4), "v"(p5) : "memory");
}
__device__ __forceinline__ void st_bypass_f32(float* p, float v) {
  asm volatile("global_store_dword %0, %1, off sc0 sc1" :: "v"(p), "v"(v) : "memory");
}
__device__ __forceinline__ void st_bypass_u16(u16* p, u16 v) {
  unsigned vv = v;
  asm volatile("global_store_short %0, %1, off sc0 sc1" :: "v"(p), "v"(vv) : "memory");
}

// sum of 16 counters spread 128B apart (single issue burst, one wait)
__device__ __forceinline__ unsigned bar_sum16(const unsigned* p) {
  unsigned a0,a1,a2,a3,a4,a5,a6,a7,a8,a9,a10,a11,a12,a13,a14,a15;
  asm volatile(
    "global_load_dword %0, %16, off sc0 sc1\n\t"
    "global_load_dword %1, %16, off offset:128 sc0 sc1\n\t"
    "global_load_dword %2, %16, off offset:256 sc0 sc1\n\t"
    "global_load_dword %3, %16, off offset:384 sc0 sc1\n\t"
    "global_load_dword %4, %16, off offset:512 sc0 sc1\n\t"
    "global_load_dword %5, %16, off offset:640 sc0 sc1\n\t"
    "global_load_dword %6, %16, off offset:768 sc0 sc1\n\t"
    "global_load_dword %7, %16, off offset:896 sc0 sc1\n\t"
    "global_load_dword %8, %16, off offset:1024 sc0 sc1\n\t"
    "global_load_dword %9, %16, off offset:1152 sc0 sc1\n\t"
    "global_load_dword %10, %16, off offset:1280 sc0 sc1\n\t"
    "global_load_dword %11, %16, off offset:1408 sc0 sc1\n\t"
    "global_load_dword %12, %16, off offset:1536 sc0 sc1\n\t"
    "global_load_dword %13, %16, off offset:1664 sc0 sc1\n\t"
    "global_load_dword %14, %16, off offset:1792 sc0 sc1\n\t"
    "global_load_dword %15, %16, off offset:1920 sc0 sc1\n\t"
    "s_waitcnt vmcnt(0)"
    : "=&v"(a0), "=&v"(a1), "=&v"(a2), "=&v"(a3), "=&v"(a4), "=&v"(a5),
      "=&v"(a6), "=&v"(a7), "=&v"(a8), "=&v"(a9), "=&v"(a10), "=&v"(a11),
      "=&v"(a12), "=&v"(a13), "=&v"(a14), "=&v"(a15)
    : "v"(p) : "memory");
  return ((a0+a1)+(a2+a3)) + ((a4+a5)+(a6+a7)) +
         ((a8+a9)+(a10+a11)) + ((a12+a13)+(a14+a15));
}

// multi-line grid barrier: arrivals spread over 16 lines; counters are
// monotonic (no reset); wait until sum >= target. No cache maintenance:
// all cross-block data moves via sc0sc1 bypass ops, and __syncthreads
// drains each wave's vmcnt before arrival.
__device__ __forceinline__ void gridbar(unsigned* bars, int line, unsigned target) {
  __syncthreads();
  if (threadIdx.x == 0) {
    asm volatile("s_waitcnt vmcnt(0) lgkmcnt(0)" ::: "memory");
    __hip_atomic_fetch_add(bars + (size_t)line * 32, 1u,
                           __ATOMIC_RELAXED, __HIP_MEMORY_SCOPE_AGENT);
    while (bar_sum16(bars) < target) __builtin_amdgcn_s_sleep(1);
  }
  __syncthreads();
}

// ---------------- prep kernels ----------------

__global__ void conv_bf(const float* __restrict__ in, u16* __restrict__ out, int n) {
  int i = blockIdx.x * blockDim.x + threadIdx.x;
  int st = gridDim.x * blockDim.x;
  for (; i < n; i += st) out[i] = f2b(in[i]);
}

__global__ void bsum_k(const float* __restrict__ a, const float* __restrict__ b,
                       float* __restrict__ o, int n) {
  int i = blockIdx.x * blockDim.x + threadIdx.x;
  if (i < n) o[i] = a[i] + b[i];
}

// out[c][r] = bf16(in[r][c]); in is R x C
__global__ void transpose_bf(const float* __restrict__ in, u16* __restrict__ out, int R, int C) {
  __shared__ float tl[64][65];
  int tid = threadIdx.x;
  int tc0 = blockIdx.x * 64, tr0 = blockIdx.y * 64;
  int cc = tid & 63;
  for (int rr = tid >> 6; rr < 64; rr += 4) {
    int rg = tr0 + rr, cg = tc0 + cc;
    tl[rr][cc] = (rg < R && cg < C) ? in[(size_t)rg * C + cg] : 0.f;
  }
  __syncthreads();
  int rr = tid & 63;
  for (int c2 = tid >> 6; c2 < 64; c2 += 4) {
    int cg = tc0 + c2, rg = tr0 + rr;
    if (cg < C && rg < R) out[(size_t)cg * R + rg] = f2b(tl[rr][c2]);
  }
}

// h0/c0 into [b][h] layout (+ bf16 mirror of h0)
__global__ __launch_bounds__(512) void init_hc(
    const float* __restrict__ enc, const float* __restrict__ W2h,
    const float* __restrict__ b2h, const float* __restrict__ W2c,
    const float* __restrict__ b2c, float* __restrict__ hT, float* __restrict__ cT,
    u16* __restrict__ hT2)
{
  __shared__ float pool[D_];
  int b = blockIdx.x, tid = threadIdx.x;
  for (int d = tid; d < D_; d += 512) {
    float s = 0.f;
    const float* ep = enc + (size_t)b * N_ * D_ + d;
    for (int n = 0; n < N_; ++n) s += ep[(size_t)n * D_];
    pool[d] = s * (1.f / 196.f);
  }
  __syncthreads();
  float a = b2h[tid], a2 = b2c[tid];
  #pragma unroll 4
  for (int d = 0; d < D_; ++d) {
    float pv = pool[d];
    a  += pv * W2h[d * H_ + tid];
    a2 += pv * W2c[d * H_ + tid];
  }
  float h0 = fast_tanh(a);
  hT[b * H_ + tid] = h0;
  hT2[b * H_ + tid] = f2b(h0);
  cT[b * H_ + tid] = fast_tanh(a2);
}

// ---------------- MFMA GEMM, B given as f32 K x N row-major (converted in-stage) ----
// AMODE: 0 = A bf16 [M][lda];  1 = A f32 with row gather via xidx (emb table)
// OUTMODE: 0 = f32 row-major; 1 = bf16 row-major; 3 = bf16 scatter [t][col][b]
template<int AMODE, int OUTMODE, int BIAS>
__global__ __launch_bounds__(256) void gemm2(
    const void* __restrict__ Av, const float* __restrict__ Bf,
    const int* __restrict__ xidx, void* __restrict__ Cv,
    const float* __restrict__ bias, int M, int N, int K, int lda)
{
  __shared__ __align__(16) u16 Al[128][72];
  __shared__ __align__(16) u16 Bl[128][72];
  const int tid = threadIdx.x;
  const int tm0 = blockIdx.y * 128, tn0 = blockIdx.x * 128;
  const int wv = tid >> 6, lane = tid & 63;
  const int wr = wv >> 1, wc = wv & 1;
  f32x4 acc[4][4] = {};
  const int r = tid >> 1, cb = (tid & 1) * 32;
  const int bkr = tid >> 5;          // 0..7
  const int bnc = (tid & 31) * 4;    // 0..124
  for (int k0 = 0; k0 < K; k0 += 64) {
    int rm = tm0 + r; if (rm >= M) rm = M - 1;
    if (AMODE == 0) {
      const u16* gp = (const u16*)Av + (size_t)rm * lda + k0 + cb;
      #pragma unroll
      for (int u = 0; u < 4; ++u)
        *(short8*)&Al[r][cb + u * 8] = *(const short8*)(gp + u * 8);
    } else {
      const float* gp = (const float*)Av + (size_t)xidx[rm] * lda + k0 + cb;
      #pragma unroll
      for (int u = 0; u < 4; ++u) {
        f32x4 a0 = *(const f32x4*)(gp + u * 8);
        f32x4 a1 = *(const f32x4*)(gp + u * 8 + 4);
        Al[r][cb + u * 8 + 0] = f2b(a0[0]); Al[r][cb + u * 8 + 1] = f2b(a0[1]);
        Al[r][cb + u * 8 + 2] = f2b(a0[2]); Al[r][cb + u * 8 + 3] = f2b(a0[3]);
        Al[r][cb + u * 8 + 4] = f2b(a1[0]); Al[r][cb + u * 8 + 5] = f2b(a1[1]);
        Al[r][cb + u * 8 + 6] = f2b(a1[2]); Al[r][cb + u * 8 + 7] = f2b(a1[3]);
      }
    }
    {
      int ncc = tn0 + bnc; if (ncc > N - 4) ncc = N - 4;
      #pragma unroll
      for (int u = 0; u < 8; ++u) {
        int kr = bkr + u * 8;
        const float* bp = Bf + (size_t)(k0 + kr) * N + ncc;
        f32x4 bv = *(const f32x4*)bp;
        #pragma unroll
        for (int j = 0; j < 4; ++j) Bl[bnc + j][kr] = f2b(bv[j]);
      }
    }
    __syncthreads();
    #pragma unroll
    for (int kk = 0; kk < 64; kk += 32) {
      short8 af[4], bfv[4];
      #pragma unroll
      for (int i = 0; i < 4; ++i)
        af[i] = *(const short8*)&Al[wr * 64 + i * 16 + (lane & 15)][kk + (lane >> 4) * 8];
      #pragma unroll
      for (int j = 0; j < 4; ++j)
        bfv[j] = *(const short8*)&Bl[wc * 64 + j * 16 + (lane & 15)][kk + (lane >> 4) * 8];
      #pragma unroll
      for (int i = 0; i < 4; ++i)
        #pragma unroll
        for (int j = 0; j < 4; ++j)
          acc[i][j] = __builtin_amdgcn_mfma_f32_16x16x32_bf16(af[i], bfv[j], acc[i][j], 0, 0, 0);
    }
    __syncthreads();
  }
  #pragma unroll
  for (int i = 0; i < 4; ++i) {
    int row0 = tm0 + wr * 64 + i * 16 + (lane >> 4) * 4;
    #pragma unroll
    for (int j = 0; j < 4; ++j) {
      int col = tn0 + wc * 64 + j * 16 + (lane & 15);
      if (col < N) {
        float bs = BIAS ? bias[col] : 0.f;
        #pragma unroll
        for (int rr2 = 0; rr2 < 4; ++rr2) {
          int row = row0 + rr2;
          if (row < M) {
            float val = acc[i][j][rr2] + bs;
            if (OUTMODE == 0) ((float*)Cv)[(size_t)row * N + col] = val;
            else if (OUTMODE == 1) ((u16*)Cv)[(size_t)row * N + col] = f2b(val);
            else {
              int tt = row & 127, bb = row >> 7;
              ((u16*)Cv)[((size_t)tt * G4H + col) * 32 + bb] = f2b(val);
            }
          }
        }
      }
    }
  }
}

// ---------------- persistent recurrent kernel ----------------
// 160 blocks x 512. blocks 0..31: attention (1 per batch); 32..159: gates
// (block gi owns h-indices gi*4..gi*4+3 across all 4 gates = 16 columns).
__global__ __launch_bounds__(512, 1) void recur3(
    const u16* __restrict__ enc_bf, const int* __restrict__ mask,
    const u16* __restrict__ Ke, const u16* __restrict__ Whbf,
    const float* __restrict__ vvec, const u16* __restrict__ WhhT,
    const u16* __restrict__ WihDT, const u16* __restrict__ g_emb,
    const float* __restrict__ cT0,
    float* hT, u16* hT2, u16* ctxB, u16* h_hist, float* out_h, float* out_c,
    unsigned* bars)
{
  __shared__ union {
    struct {
      float h[512];
      float hw8[512];       // [j][64]: hw8[(col&7)*64 + (col>>3)]
      float sl[256];
      float maskadd[256];
      float part[8][768];
      float rd;
    } at;                                     // ~30KB
    struct { u32x4 hst[64 * 32]; } g1;        // h bf16 chunks [kc][b], 32KB
    struct { u32x4 ctx[96 * 32]; } g2;        // ctx bf16 chunks [kc][b], 48KB
  } su;
  __shared__ float g1l[16][32];
  __shared__ float gpre[16][32];
  __shared__ float cfl[4][32];

  const int bid = blockIdx.x, tid = threadIdx.x;
  const int lane = tid & 63, wvx = tid >> 6;
  const bool is_attn = bid < NATT;
  const int b_at = bid;
  const int gi = bid - NATT;          // 0..127
  const int hbase = gi * 4;
  const int p_ = lane >> 5, bb_ = lane & 31;
  const int line = bid & 15;

  float vreg[8];
  if (is_attn) {
    #pragma unroll
    for (int j = 0; j < 8; ++j) vreg[j] = vvec[lane * 8 + j];
    for (int nn = tid; nn < N_; nn += 512)
      su.at.maskadd[nn] = (mask[b_at * N_ + nn] == 0) ? -1e9f : 0.f;
  } else {
    if (tid < 128) {
      int bb = tid & 31, j2 = tid >> 5;
      cfl[j2][bb] = cT0[bb * H_ + hbase + j2];
    }
  }
  __syncthreads();

  unsigned tgt = 0;
  for (int t = 0; t < T_; ++t) {
    // ================= Phase 1 =================
    if (is_attn) {
      su.at.h[tid] = ld_bypass_f32(hT + b_at * H_ + tid);
      __syncthreads();
      // hw[col] = sum_k h[k]*Wh[k][col]; lane owns 8 cols, waves split k
      {
        float acc8[8] = {0,0,0,0,0,0,0,0};
        #pragma unroll 4
        for (int kk = 0; kk < 64; ++kk) {
          int k = wvx * 64 + kk;
          float hk = su.at.h[k];
          short8 w = *(const short8*)(Whbf + (size_t)k * H_ + lane * 8);
          #pragma unroll
          for (int j = 0; j < 8; ++j) acc8[j] += hk * b2f((u16)w[j]);
        }
        f32x4 v0 = {acc8[0], acc8[1], acc8[2], acc8[3]};
        f32x4 v1 = {acc8[4], acc8[5], acc8[6], acc8[7]};
        *(f32x4*)&su.at.part[wvx][lane * 8] = v0;
        *(f32x4*)&su.at.part[wvx][lane * 8 + 4] = v1;
      }
      __syncthreads();
      {
        float s = 0.f;
        #pragma unroll
        for (int w = 0; w < 8; ++w) s += su.at.part[w][tid];
        su.at.hw8[(tid & 7) * 64 + (tid >> 3)] = s;   // hw8[j][col>>3] = hw[col]
      }
      __syncthreads();
      // scores: full-wave reduction; lane covers Ke[n][lane*8..lane*8+7]
      for (int nn = wvx; nn < N_; nn += 8) {
        short8 kv = *(const short8*)(Ke + ((size_t)(b_at * N_ + nn)) * H_ + lane * 8);
        float p = 0.f;
        #pragma unroll
        for (int j = 0; j < 8; ++j)
          p += vreg[j] * fast_tanh(su.at.hw8[j * 64 + lane] + b2f((u16)kv[j]));
        p = wred_sum(p);
        if (lane == 0) su.at.sl[nn] = p + su.at.maskadd[nn];
      }
      __syncthreads();
      // softmax stats (wave 0), exp in place
      if (wvx == 0) {
        float m = -3.4e38f;
        for (int nn = lane; nn < N_; nn += 64) m = fmaxf(m, su.at.sl[nn]);
        m = wred_max(m);
        float s = 0.f;
        for (int nn = lane; nn < N_; nn += 64) {
          float e = __expf(su.at.sl[nn] - m);
          su.at.sl[nn] = e; s += e;
        }
        s = wred_sum(s);
        if (lane == 0) su.at.rd = 1.f / s;
      }
      __syncthreads();
      // context partials (coalesced short8 enc reads)
      {
        float acc0[8] = {0,0,0,0,0,0,0,0}, acc1[8] = {0,0,0,0,0,0,0,0};
        for (int nn = wvx; nn < N_; nn += 8) {
          float al = su.at.sl[nn];
          const u16* ep = enc_bf + ((size_t)(b_at * N_ + nn)) * D_;
          short8 e0 = *(const short8*)(ep + lane * 8);
          #pragma unroll
          for (int j = 0; j < 8; ++j) acc0[j] += al * b2f((u16)e0[j]);
          if (lane < 32) {
            short8 e1 = *(const short8*)(ep + 512 + lane * 8);
            #pragma unroll
            for (int j = 0; j < 8; ++j) acc1[j] += al * b2f((u16)e1[j]);
          }
        }
        f32x4 v0 = {acc0[0], acc0[1], acc0[2], acc0[3]};
        f32x4 v1 = {acc0[4], acc0[5], acc0[6], acc0[7]};
        *(f32x4*)&su.at.part[wvx][lane * 8] = v0;
        *(f32x4*)&su.at.part[wvx][lane * 8 + 4] = v1;
        if (lane < 32) {
          f32x4 v2 = {acc1[0], acc1[1], acc1[2], acc1[3]};
          f32x4 v3 = {acc1[4], acc1[5], acc1[6], acc1[7]};
          *(f32x4*)&su.at.part[wvx][512 + lane * 8] = v2;
          *(f32x4*)&su.at.part[wvx][512 + lane * 8 + 4] = v3;
        }
      }
      __syncthreads();
      {
        float rD = su.at.rd;
        for (int d = tid; d < D_; d += 512) {
          float s = 0.f;
          #pragma unroll
          for (int w = 0; w < 8; ++w) s += su.at.part[w][d];
          st_bypass_u16(ctxB + b_at * D_ + d, f2b(s * rD));
        }
      }
    } else {
      // stage hT2 (bf16) -> LDS chunks [kc][b]
      {
        const int b0 = tid & 31, kc0 = tid >> 5;
        const u16* hp = hT2 + b0 * H_;
        u32x4 v0, v1, v2, v3;
        ld4_bypass(hp + kc0 * 8, hp + (kc0 + 16) * 8,
                   hp + (kc0 + 32) * 8, hp + (kc0 + 48) * 8, v0, v1, v2, v3);
        su.g1.hst[(kc0     ) * 32 + b0] = v0;
        su.g1.hst[(kc0 + 16) * 32 + b0] = v1;
        su.g1.hst[(kc0 + 32) * 32 + b0] = v2;
        su.g1.hst[(kc0 + 48) * 32 + b0] = v3;
      }
      __syncthreads();
      #pragma unroll
      for (int c2 = 0; c2 < 2; ++c2) {
        int colidx = wvx * 2 + c2;
        int col = (colidx >> 2) * H_ + hbase + (colidx & 3);
        const u16* wp = WhhT + (size_t)col * H_ + p_ * 256;
        float a = 0.f;
        #pragma unroll 4
        for (int k8 = 0; k8 < 32; ++k8) {
          short8 w = *(const short8*)(wp + k8 * 8);
          short8 h8 = *(const short8*)&su.g1.hst[(p_ * 32 + k8) * 32 + bb_];
          #pragma unroll
          for (int j = 0; j < 8; ++j) a += b2f((u16)w[j]) * b2f((u16)h8[j]);
        }
        a += __shfl_xor(a, 32, 64);
        if (p_ == 0) {
          float ge = b2f(g_emb[((size_t)t * G4H + col) * 32 + bb_]);
          g1l[colidx][bb_] = a + ge;
        }
      }
    }
    tgt += NBLK;
    gridbar(bars, line, tgt);

    // ================= Phase 2 (gate blocks) =================
    if (!is_attn) {
      // stage ctx (bf16) -> LDS chunks [kc][b]
      {
        const int b0 = tid & 31, kc0 = tid >> 5;
        const u16* cp = ctxB + b0 * D_;
        u32x4 w0, w1, w2, w3, w4, w5;
        ld6_bypass(cp + kc0 * 8, cp + (kc0 + 16) * 8, cp + (kc0 + 32) * 8,
                   cp + (kc0 + 48) * 8, cp + (kc0 + 64) * 8, cp + (kc0 + 80) * 8,
                   w0, w1, w2, w3, w4, w5);
        su.g2.ctx[(kc0     ) * 32 + b0] = w0;
        su.g2.ctx[(kc0 + 16) * 32 + b0] = w1;
        su.g2.ctx[(kc0 + 32) * 32 + b0] = w2;
        su.g2.ctx[(kc0 + 48) * 32 + b0] = w3;
        su.g2.ctx[(kc0 + 64) * 32 + b0] = w4;
        su.g2.ctx[(kc0 + 80) * 32 + b0] = w5;
      }
      __syncthreads();
      #pragma unroll
      for (int c2 = 0; c2 < 2; ++c2) {
        int colidx = wvx * 2 + c2;
        int col = (colidx >> 2) * H_ + hbase + (colidx & 3);
        const u16* wp = WihDT + (size_t)col * D_ + p_ * 384;
        float a = 0.f;
        #pragma unroll 4
        for (int i = 0; i < 48; ++i) {
          short8 w = *(const short8*)(wp + i * 8);
          short8 cx = *(const short8*)&su.g2.ctx[(p_ * 48 + i) * 32 + bb_];
          #pragma unroll
          for (int j = 0; j < 8; ++j) a += b2f((u16)w[j]) * b2f((u16)cx[j]);
        }
        a += __shfl_xor(a, 32, 64);
        if (p_ == 0) gpre[colidx][bb_] = a + g1l[colidx][bb_];
      }
      __syncthreads();
      if (tid < 128) {
        int bb = tid & 31, j2 = tid >> 5;
        int hidx = hbase + j2;
        float gI = gpre[j2][bb], gF = gpre[4 + j2][bb];
        float gG = gpre[8 + j2][bb], gO = gpre[12 + j2][bb];
        float co = cfl[j2][bb];
        float cn = sigm(gF) * co + sigm(gI) * fast_tanh(gG);
        float hn = sigm(gO) * fast_tanh(cn);
        cfl[j2][bb] = cn;
        st_bypass_f32(hT + bb * H_ + hidx, hn);
        st_bypass_u16(hT2 + bb * H_ + hidx, f2b(hn));
        st_bypass_u16(h_hist + ((size_t)bb * T_ + t) * H_ + hidx, f2b(hn));
        if (t == T_ - 1) {
          out_h[bb * H_ + hidx] = hn;
          out_c[bb * H_ + hidx] = cn;
        }
      }
    }
    tgt += NBLK;
    gridbar(bars, line, tgt);
  }
}

extern "C" void kernel_launch(void* const* d_in, const int* in_sizes, int n_in,
                              void* d_out, int out_size, void* d_ws, size_t ws_size,
                              hipStream_t stream) {
  const int*   x    = (const int*)d_in[0];
  const float* enc  = (const float*)d_in[1];
  const int*   mask = (const int*)d_in[2];
  const float* emb  = (const float*)d_in[3];
  const float* We   = (const float*)d_in[4];
  const float* Wh   = (const float*)d_in[5];
  const float* v    = (const float*)d_in[6];
  const float* Wih  = (const float*)d_in[7];
  const float* Whh  = (const float*)d_in[8];
  const float* bih  = (const float*)d_in[9];
  const float* bhh  = (const float*)d_in[10];
  const float* fcW  = (const float*)d_in[11];
  const float* fcb  = (const float*)d_in[12];
  const float* W2h  = (const float*)d_in[13];
  const float* b2h  = (const float*)d_in[14];
  const float* W2c  = (const float*)d_in[15];
  const float* b2c  = (const float*)d_in[16];
  float* out = (float*)d_out;

  char* ws = (char*)d_ws;
  u16* enc_bf = (u16*)(ws + O_ENCBF);
  u16* Whbf   = (u16*)(ws + O_WHBFR);
  u16* WhhT   = (u16*)(ws + O_WHHT);
  u16* WihDT  = (u16*)(ws + O_WIHDT);
  u16* Ke     = (u16*)(ws + O_KE);
  u16* g_emb  = (u16*)(ws + O_GEMB);
  float* bsum = (float*)(ws + O_BSUM);
  float* hT   = (float*)(ws + O_HT);
  float* cT   = (float*)(ws + O_CT);
  u16* ctxB   = (u16*)(ws + O_CTX);
  u16* h_hist = (u16*)(ws + O_HIST);
  unsigned* bars = (unsigned*)(ws + O_BARS);
  u16* hT2    = (u16*)(ws + O_HT2);

  hipMemsetAsync(bars, 0, 2048, stream);
  conv_bf<<<1024, 256, 0, stream>>>(enc, enc_bf, B_ * N_ * D_);
  conv_bf<<<256, 256, 0, stream>>>(Wh, Whbf, H_ * H_);
  transpose_bf<<<dim3(32, 8), 256, 0, stream>>>(Whh, WhhT, H_, G4H);
  transpose_bf<<<dim3(32, 12), 256, 0, stream>>>(Wih + (size_t)E_ * G4H, WihDT, D_, G4H);
  bsum_k<<<8, 256, 0, stream>>>(bih, bhh, bsum, G4H);
  init_hc<<<32, 512, 0, stream>>>(enc, W2h, b2h, W2c, b2c, hT, cT, hT2);
  // Ke = enc_bf @ We   (6272 x 512, K=768) -> bf16 row-major
  gemm2<0, 1, 0><<<dim3(4, 49), 256, 0, stream>>>(enc_bf, We, nullptr, (void*)Ke,
                                                  nullptr, B_ * N_, H_, D_, D_);
  // g_emb[t][col][b] = emb[x] @ Wih[:256] + bih + bhh  (4096 x 2048, K=256)
  gemm2<1, 3, 1><<<dim3(16, 32), 256, 0, stream>>>(emb, Wih, x, (void*)g_emb,
                                                   bsum, B_ * T_, G4H, E_, E_);
  recur3<<<NBLK, 512, 0, stream>>>(enc_bf, mask, Ke, Whbf, v, WhhT, WihDT, g_emb,
                                   cT, hT, hT2, ctxB, h_hist,
                                   out + (size_t)B_ * T_ * V_,
                                   out + (size_t)B_ * T_ * V_ + B_ * H_, bars);
  // logits = h_hist @ fcW + fcb  (4096 x 10000, K=512) -> f32
  gemm2<0, 0, 1><<<dim3(79, 32), 256, 0, stream>>>(h_hist, fcW, nullptr, (void*)out,
                                                   fcb, B_ * T_, V_, H_, H_);
}

// Round 6
// 7601.134 us; speedup vs baseline: 3.4890x; 1.0879x over previous
//
#include <hip/hip_runtime.h>

typedef unsigned short u16;
typedef __attribute__((ext_vector_type(8))) short short8;
typedef __attribute__((ext_vector_type(4))) float f32x4;
typedef __attribute__((ext_vector_type(4))) unsigned int u32x4;

#define B_  32
#define T_  128
#define N_  196
#define D_  768
#define E_  256
#define H_  512
#define V_  10000
#define G4H 2048
#define NATT 32
#define NGATE 128
#define NBLK 160

// workspace offsets (bytes), all 256-aligned
#define O_ENCBF 0UL            // 9,633,792   enc bf16 [32][196][768]
#define O_WHBFR 9633792UL      // 524,288     Wh bf16 row-major [k][col]
#define O_WHHT  10158080UL     // 2,097,152   WhhT [2048 col][512 k]
#define O_WIHDT 12255232UL     // 3,145,728   WihDT[2048 col][768 d]
#define O_KE    15400960UL     // 6,422,528   Ke bf16 [6272][512]
#define O_GEMB  21823488UL     // 16,777,216  g_emb bf16 [128 t][2048 col][32 b]
#define O_BSUM  38600704UL     // 8,192       bih+bhh
#define O_HT    38608896UL     // 65,536      h f32 [32][512]
#define O_CT    38674432UL     // 65,536      c0 f32 [32][512]
#define O_CTX   38739968UL     // 49,152      ctx bf16 [32][768]
#define O_HIST  38789120UL     // 4,194,304   h_hist bf16 [32*128][512]
#define O_BARS  42983424UL     // 2,048       16 arrival lines x 128B
#define O_HT2   42985472UL     // 32,768      h bf16 [32][512]
#define O_REL   43018240UL     // 20,480      160 release lines x 128B

__device__ __forceinline__ float b2f(u16 u) {
  union { unsigned i; float f; } c; c.i = ((unsigned)u) << 16; return c.f;
}
__device__ __forceinline__ u16 f2b(float f) {   // RNE f32->bf16
  unsigned u = __float_as_uint(f);
  unsigned r = (u + 0x7fffu + ((u >> 16) & 1u)) >> 16;
  return (u16)r;
}
__device__ __forceinline__ float fast_tanh(float x) {
  float e = __expf(2.f * x);
  return 1.f - 2.f * __builtin_amdgcn_rcpf(e + 1.f);
}
__device__ __forceinline__ float sigm(float x) {
  return __builtin_amdgcn_rcpf(1.f + __expf(-x));
}
__device__ __forceinline__ float wred_sum(float x) {
  #pragma unroll
  for (int o = 32; o; o >>= 1) x += __shfl_xor(x, o, 64);
  return x;
}
__device__ __forceinline__ float wred_max(float x) {
  #pragma unroll
  for (int o = 32; o; o >>= 1) x = fmaxf(x, __shfl_xor(x, o, 64));
  return x;
}

// ---- L2-bypass (device-coherent) ops: read/write at the coherence point ----
__device__ __forceinline__ float ld_bypass_f32(const float* p) {
  float v;
  asm volatile("global_load_dword %0, %1, off sc0 sc1\n\ts_waitcnt vmcnt(0)"
               : "=v"(v) : "v"(p) : "memory");
  return v;
}
__device__ __forceinline__ unsigned ld_bypass_u32(const unsigned* p) {
  unsigned v;
  asm volatile("global_load_dword %0, %1, off sc0 sc1\n\ts_waitcnt vmcnt(0)"
               : "=v"(v) : "v"(p) : "memory");
  return v;
}
__device__ __forceinline__ void ld4_bypass(const void* p0, const void* p1,
                                           const void* p2, const void* p3,
                                           u32x4& a, u32x4& b, u32x4& c, u32x4& d) {
  asm volatile(
    "global_load_dwordx4 %0, %4, off sc0 sc1\n\t"
    "global_load_dwordx4 %1, %5, off sc0 sc1\n\t"
    "global_load_dwordx4 %2, %6, off sc0 sc1\n\t"
    "global_load_dwordx4 %3, %7, off sc0 sc1\n\t"
    "s_waitcnt vmcnt(0)"
    : "=&v"(a), "=&v"(b), "=&v"(c), "=&v"(d)
    : "v"(p0), "v"(p1), "v"(p2), "v"(p3) : "memory");
}
__device__ __forceinline__ void ld6_bypass(const void* p0, const void* p1,
    const void* p2, const void* p3, const void* p4, const void* p5,
    u32x4& a, u32x4& b, u32x4& c, u32x4& d, u32x4& e, u32x4& f) {
  asm volatile(
    "global_load_dwordx4 %0, %6, off sc0 sc1\n\t"
    "global_load_dwordx4 %1, %7, off sc0 sc1\n\t"
    "global_load_dwordx4 %2, %8, off sc0 sc1\n\t"
    "global_load_dwordx4 %3, %9, off sc0 sc1\n\t"
    "global_load_dwordx4 %4, %10, off sc0 sc1\n\t"
    "global_load_dwordx4 %5, %11, off sc0 sc1\n\t"
    "s_waitcnt vmcnt(0)"
    : "=&v"(a), "=&v"(b), "=&v"(c), "=&v"(d), "=&v"(e), "=&v"(f)
    : "v"(p0), "v"(p1), "v"(p2), "v"(p3), "v"(p4), "v"(p5) : "memory");
}
__device__ __forceinline__ void st_bypass_f32(float* p, float v) {
  asm volatile("global_store_dword %0, %1, off sc0 sc1" :: "v"(p), "v"(v) : "memory");
}
__device__ __forceinline__ void st_bypass_u32(unsigned* p, unsigned v) {
  asm volatile("global_store_dword %0, %1, off sc0 sc1" :: "v"(p), "v"(v) : "memory");
}
__device__ __forceinline__ void st_bypass_u16(u16* p, u16 v) {
  unsigned vv = v;
  asm volatile("global_store_short %0, %1, off sc0 sc1" :: "v"(p), "v"(vv) : "memory");
}

// sum of 16 counters spread 128B apart (single issue burst, one wait)
__device__ __forceinline__ unsigned bar_sum16(const unsigned* p) {
  unsigned a0,a1,a2,a3,a4,a5,a6,a7,a8,a9,a10,a11,a12,a13,a14,a15;
  asm volatile(
    "global_load_dword %0, %16, off sc0 sc1\n\t"
    "global_load_dword %1, %16, off offset:128 sc0 sc1\n\t"
    "global_load_dword %2, %16, off offset:256 sc0 sc1\n\t"
    "global_load_dword %3, %16, off offset:384 sc0 sc1\n\t"
    "global_load_dword %4, %16, off offset:512 sc0 sc1\n\t"
    "global_load_dword %5, %16, off offset:640 sc0 sc1\n\t"
    "global_load_dword %6, %16, off offset:768 sc0 sc1\n\t"
    "global_load_dword %7, %16, off offset:896 sc0 sc1\n\t"
    "global_load_dword %8, %16, off offset:1024 sc0 sc1\n\t"
    "global_load_dword %9, %16, off offset:1152 sc0 sc1\n\t"
    "global_load_dword %10, %16, off offset:1280 sc0 sc1\n\t"
    "global_load_dword %11, %16, off offset:1408 sc0 sc1\n\t"
    "global_load_dword %12, %16, off offset:1536 sc0 sc1\n\t"
    "global_load_dword %13, %16, off offset:1664 sc0 sc1\n\t"
    "global_load_dword %14, %16, off offset:1792 sc0 sc1\n\t"
    "global_load_dword %15, %16, off offset:1920 sc0 sc1\n\t"
    "s_waitcnt vmcnt(0)"
    : "=&v"(a0), "=&v"(a1), "=&v"(a2), "=&v"(a3), "=&v"(a4), "=&v"(a5),
      "=&v"(a6), "=&v"(a7), "=&v"(a8), "=&v"(a9), "=&v"(a10), "=&v"(a11),
      "=&v"(a12), "=&v"(a13), "=&v"(a14), "=&v"(a15)
    : "v"(p) : "memory");
  return ((a0+a1)+(a2+a3)) + ((a4+a5)+(a6+a7)) +
         ((a8+a9)+(a10+a11)) + ((a12+a13)+(a14+a15));
}

// master-detect + private-line broadcast grid barrier.
// Arrivals: atomic add on 16 spread lines (~10 blocks/line).
// ONLY block 0 thread 0 polls the arrival lines (no poll storm vs atomics).
// On detect, master block threads 0..NBLK-1 store the target tag to each
// block's PRIVATE release line; every other block polls only its own line
// (1 writer / 1 reader -> zero contention). All cross-block data moves via
// sc0sc1 bypass ops and __syncthreads drains vmcnt before arrival, so no
// cache maintenance is needed anywhere.
__device__ __forceinline__ void gridbar(unsigned* bars, unsigned* rel,
                                        int bid, unsigned target) {
  __syncthreads();
  if (bid == 0) {
    if (threadIdx.x == 0) {
      asm volatile("s_waitcnt vmcnt(0) lgkmcnt(0)" ::: "memory");
      __hip_atomic_fetch_add(bars, 1u, __ATOMIC_RELAXED, __HIP_MEMORY_SCOPE_AGENT);
      while (bar_sum16(bars) < target) __builtin_amdgcn_s_sleep(1);
    }
    __syncthreads();
    if (threadIdx.x < NBLK) st_bypass_u32(rel + (size_t)threadIdx.x * 32, target);
  } else {
    if (threadIdx.x == 0) {
      asm volatile("s_waitcnt vmcnt(0) lgkmcnt(0)" ::: "memory");
      __hip_atomic_fetch_add(bars + (size_t)(bid & 15) * 32, 1u,
                             __ATOMIC_RELAXED, __HIP_MEMORY_SCOPE_AGENT);
      while (ld_bypass_u32(rel + (size_t)bid * 32) < target)
        __builtin_amdgcn_s_sleep(2);
    }
    __syncthreads();
  }
}

// ---------------- prep kernels ----------------

__global__ void conv_bf(const float* __restrict__ in, u16* __restrict__ out, int n) {
  int i = blockIdx.x * blockDim.x + threadIdx.x;
  int st = gridDim.x * blockDim.x;
  for (; i < n; i += st) out[i] = f2b(in[i]);
}

__global__ void bsum_k(const float* __restrict__ a, const float* __restrict__ b,
                       float* __restrict__ o, int n) {
  int i = blockIdx.x * blockDim.x + threadIdx.x;
  if (i < n) o[i] = a[i] + b[i];
}

// out[c][r] = bf16(in[r][c]); in is R x C
__global__ void transpose_bf(const float* __restrict__ in, u16* __restrict__ out, int R, int C) {
  __shared__ float tl[64][65];
  int tid = threadIdx.x;
  int tc0 = blockIdx.x * 64, tr0 = blockIdx.y * 64;
  int cc = tid & 63;
  for (int rr = tid >> 6; rr < 64; rr += 4) {
    int rg = tr0 + rr, cg = tc0 + cc;
    tl[rr][cc] = (rg < R && cg < C) ? in[(size_t)rg * C + cg] : 0.f;
  }
  __syncthreads();
  int rr = tid & 63;
  for (int c2 = tid >> 6; c2 < 64; c2 += 4) {
    int cg = tc0 + c2, rg = tr0 + rr;
    if (cg < C && rg < R) out[(size_t)cg * R + rg] = f2b(tl[rr][c2]);
  }
}

// h0/c0 into [b][h] layout (+ bf16 mirror of h0)
__global__ __launch_bounds__(512) void init_hc(
    const float* __restrict__ enc, const float* __restrict__ W2h,
    const float* __restrict__ b2h, const float* __restrict__ W2c,
    const float* __restrict__ b2c, float* __restrict__ hT, float* __restrict__ cT,
    u16* __restrict__ hT2)
{
  __shared__ float pool[D_];
  int b = blockIdx.x, tid = threadIdx.x;
  for (int d = tid; d < D_; d += 512) {
    float s = 0.f;
    const float* ep = enc + (size_t)b * N_ * D_ + d;
    for (int n = 0; n < N_; ++n) s += ep[(size_t)n * D_];
    pool[d] = s * (1.f / 196.f);
  }
  __syncthreads();
  float a = b2h[tid], a2 = b2c[tid];
  #pragma unroll 4
  for (int d = 0; d < D_; ++d) {
    float pv = pool[d];
    a  += pv * W2h[d * H_ + tid];
    a2 += pv * W2c[d * H_ + tid];
  }
  float h0 = fast_tanh(a);
  hT[b * H_ + tid] = h0;
  hT2[b * H_ + tid] = f2b(h0);
  cT[b * H_ + tid] = fast_tanh(a2);
}

// ---------------- MFMA GEMM, B given as f32 K x N row-major (converted in-stage) ----
// AMODE: 0 = A bf16 [M][lda];  1 = A f32 with row gather via xidx (emb table)
// OUTMODE: 0 = f32 row-major; 1 = bf16 row-major; 3 = bf16 scatter [t][col][b]
template<int AMODE, int OUTMODE, int BIAS>
__global__ __launch_bounds__(256) void gemm2(
    const void* __restrict__ Av, const float* __restrict__ Bf,
    const int* __restrict__ xidx, void* __restrict__ Cv,
    const float* __restrict__ bias, int M, int N, int K, int lda)
{
  __shared__ __align__(16) u16 Al[128][72];
  __shared__ __align__(16) u16 Bl[128][72];
  const int tid = threadIdx.x;
  const int tm0 = blockIdx.y * 128, tn0 = blockIdx.x * 128;
  const int wv = tid >> 6, lane = tid & 63;
  const int wr = wv >> 1, wc = wv & 1;
  f32x4 acc[4][4] = {};
  const int r = tid >> 1, cb = (tid & 1) * 32;
  const int bkr = tid >> 5;          // 0..7
  const int bnc = (tid & 31) * 4;    // 0..124
  for (int k0 = 0; k0 < K; k0 += 64) {
    int rm = tm0 + r; if (rm >= M) rm = M - 1;
    if (AMODE == 0) {
      const u16* gp = (const u16*)Av + (size_t)rm * lda + k0 + cb;
      #pragma unroll
      for (int u = 0; u < 4; ++u)
        *(short8*)&Al[r][cb + u * 8] = *(const short8*)(gp + u * 8);
    } else {
      const float* gp = (const float*)Av + (size_t)xidx[rm] * lda + k0 + cb;
      #pragma unroll
      for (int u = 0; u < 4; ++u) {
        f32x4 a0 = *(const f32x4*)(gp + u * 8);
        f32x4 a1 = *(const f32x4*)(gp + u * 8 + 4);
        Al[r][cb + u * 8 + 0] = f2b(a0[0]); Al[r][cb + u * 8 + 1] = f2b(a0[1]);
        Al[r][cb + u * 8 + 2] = f2b(a0[2]); Al[r][cb + u * 8 + 3] = f2b(a0[3]);
        Al[r][cb + u * 8 + 4] = f2b(a1[0]); Al[r][cb + u * 8 + 5] = f2b(a1[1]);
        Al[r][cb + u * 8 + 6] = f2b(a1[2]); Al[r][cb + u * 8 + 7] = f2b(a1[3]);
      }
    }
    {
      int ncc = tn0 + bnc; if (ncc > N - 4) ncc = N - 4;
      #pragma unroll
      for (int u = 0; u < 8; ++u) {
        int kr = bkr + u * 8;
        const float* bp = Bf + (size_t)(k0 + kr) * N + ncc;
        f32x4 bv = *(const f32x4*)bp;
        #pragma unroll
        for (int j = 0; j < 4; ++j) Bl[bnc + j][kr] = f2b(bv[j]);
      }
    }
    __syncthreads();
    #pragma unroll
    for (int kk = 0; kk < 64; kk += 32) {
      short8 af[4], bfv[4];
      #pragma unroll
      for (int i = 0; i < 4; ++i)
        af[i] = *(const short8*)&Al[wr * 64 + i * 16 + (lane & 15)][kk + (lane >> 4) * 8];
      #pragma unroll
      for (int j = 0; j < 4; ++j)
        bfv[j] = *(const short8*)&Bl[wc * 64 + j * 16 + (lane & 15)][kk + (lane >> 4) * 8];
      #pragma unroll
      for (int i = 0; i < 4; ++i)
        #pragma unroll
        for (int j = 0; j < 4; ++j)
          acc[i][j] = __builtin_amdgcn_mfma_f32_16x16x32_bf16(af[i], bfv[j], acc[i][j], 0, 0, 0);
    }
    __syncthreads();
  }
  #pragma unroll
  for (int i = 0; i < 4; ++i) {
    int row0 = tm0 + wr * 64 + i * 16 + (lane >> 4) * 4;
    #pragma unroll
    for (int j = 0; j < 4; ++j) {
      int col = tn0 + wc * 64 + j * 16 + (lane & 15);
      if (col < N) {
        float bs = BIAS ? bias[col] : 0.f;
        #pragma unroll
        for (int rr2 = 0; rr2 < 4; ++rr2) {
          int row = row0 + rr2;
          if (row < M) {
            float val = acc[i][j][rr2] + bs;
            if (OUTMODE == 0) ((float*)Cv)[(size_t)row * N + col] = val;
            else if (OUTMODE == 1) ((u16*)Cv)[(size_t)row * N + col] = f2b(val);
            else {
              int tt = row & 127, bb = row >> 7;
              ((u16*)Cv)[((size_t)tt * G4H + col) * 32 + bb] = f2b(val);
            }
          }
        }
      }
    }
  }
}

// ---------------- persistent recurrent kernel ----------------
// 160 blocks x 512. blocks 0..31: attention (1 per batch); 32..159: gates
// (block gi owns h-indices gi*4..gi*4+3 across all 4 gates = 16 columns).
__global__ __launch_bounds__(512, 1) void recur3(
    const u16* __restrict__ enc_bf, const int* __restrict__ mask,
    const u16* __restrict__ Ke, const u16* __restrict__ Whbf,
    const float* __restrict__ vvec, const u16* __restrict__ WhhT,
    const u16* __restrict__ WihDT, const u16* __restrict__ g_emb,
    const float* __restrict__ cT0,
    float* hT, u16* hT2, u16* ctxB, u16* h_hist, float* out_h, float* out_c,
    unsigned* bars, unsigned* rel)
{
  __shared__ union {
    struct {
      float h[512];
      float hw8[512];       // [j][64]: hw8[(col&7)*64 + (col>>3)]
      float sl[256];
      float maskadd[256];
      float part[8][768];
      float rd;
    } at;                                     // ~30KB
    struct { u32x4 hst[64 * 32]; } g1;        // h bf16 chunks [kc][b], 32KB
    struct { u32x4 ctx[96 * 32]; } g2;        // ctx bf16 chunks [kc][b], 48KB
  } su;
  __shared__ float g1l[16][32];
  __shared__ float gpre[16][32];
  __shared__ float cfl[4][32];

  const int bid = blockIdx.x, tid = threadIdx.x;
  const int lane = tid & 63, wvx = tid >> 6;
  const bool is_attn = bid < NATT;
  const int b_at = bid;
  const int gi = bid - NATT;          // 0..127
  const int hbase = gi * 4;
  const int p_ = lane >> 5, bb_ = lane & 31;

  float vreg[8];
  if (is_attn) {
    #pragma unroll
    for (int j = 0; j < 8; ++j) vreg[j] = vvec[lane * 8 + j];
    for (int nn = tid; nn < N_; nn += 512)
      su.at.maskadd[nn] = (mask[b_at * N_ + nn] == 0) ? -1e9f : 0.f;
  } else {
    if (tid < 128) {
      int bb = tid & 31, j2 = tid >> 5;
      cfl[j2][bb] = cT0[bb * H_ + hbase + j2];
    }
  }
  __syncthreads();

  unsigned tgt = 0;
  for (int t = 0; t < T_; ++t) {
    // ================= Phase 1 =================
    if (is_attn) {
      su.at.h[tid] = ld_bypass_f32(hT + b_at * H_ + tid);
      __syncthreads();
      // hw[col] = sum_k h[k]*Wh[k][col]; lane owns 8 cols, waves split k
      {
        float acc8[8] = {0,0,0,0,0,0,0,0};
        #pragma unroll 4
        for (int kk = 0; kk < 64; ++kk) {
          int k = wvx * 64 + kk;
          float hk = su.at.h[k];
          short8 w = *(const short8*)(Whbf + (size_t)k * H_ + lane * 8);
          #pragma unroll
          for (int j = 0; j < 8; ++j) acc8[j] += hk * b2f((u16)w[j]);
        }
        f32x4 v0 = {acc8[0], acc8[1], acc8[2], acc8[3]};
        f32x4 v1 = {acc8[4], acc8[5], acc8[6], acc8[7]};
        *(f32x4*)&su.at.part[wvx][lane * 8] = v0;
        *(f32x4*)&su.at.part[wvx][lane * 8 + 4] = v1;
      }
      __syncthreads();
      {
        float s = 0.f;
        #pragma unroll
        for (int w = 0; w < 8; ++w) s += su.at.part[w][tid];
        su.at.hw8[(tid & 7) * 64 + (tid >> 3)] = s;   // hw8[j][col>>3] = hw[col]
      }
      __syncthreads();
      // scores: full-wave reduction; lane covers Ke[n][lane*8..lane*8+7]
      for (int nn = wvx; nn < N_; nn += 8) {
        short8 kv = *(const short8*)(Ke + ((size_t)(b_at * N_ + nn)) * H_ + lane * 8);
        float p = 0.f;
        #pragma unroll
        for (int j = 0; j < 8; ++j)
          p += vreg[j] * fast_tanh(su.at.hw8[j * 64 + lane] + b2f((u16)kv[j]));
        p = wred_sum(p);
        if (lane == 0) su.at.sl[nn] = p + su.at.maskadd[nn];
      }
      __syncthreads();
      // softmax stats (wave 0), exp in place
      if (wvx == 0) {
        float m = -3.4e38f;
        for (int nn = lane; nn < N_; nn += 64) m = fmaxf(m, su.at.sl[nn]);
        m = wred_max(m);
        float s = 0.f;
        for (int nn = lane; nn < N_; nn += 64) {
          float e = __expf(su.at.sl[nn] - m);
          su.at.sl[nn] = e; s += e;
        }
        s = wred_sum(s);
        if (lane == 0) su.at.rd = 1.f / s;
      }
      __syncthreads();
      // context partials (coalesced short8 enc reads)
      {
        float acc0[8] = {0,0,0,0,0,0,0,0}, acc1[8] = {0,0,0,0,0,0,0,0};
        for (int nn = wvx; nn < N_; nn += 8) {
          float al = su.at.sl[nn];
          const u16* ep = enc_bf + ((size_t)(b_at * N_ + nn)) * D_;
          short8 e0 = *(const short8*)(ep + lane * 8);
          #pragma unroll
          for (int j = 0; j < 8; ++j) acc0[j] += al * b2f((u16)e0[j]);
          if (lane < 32) {
            short8 e1 = *(const short8*)(ep + 512 + lane * 8);
            #pragma unroll
            for (int j = 0; j < 8; ++j) acc1[j] += al * b2f((u16)e1[j]);
          }
        }
        f32x4 v0 = {acc0[0], acc0[1], acc0[2], acc0[3]};
        f32x4 v1 = {acc0[4], acc0[5], acc0[6], acc0[7]};
        *(f32x4*)&su.at.part[wvx][lane * 8] = v0;
        *(f32x4*)&su.at.part[wvx][lane * 8 + 4] = v1;
        if (lane < 32) {
          f32x4 v2 = {acc1[0], acc1[1], acc1[2], acc1[3]};
          f32x4 v3 = {acc1[4], acc1[5], acc1[6], acc1[7]};
          *(f32x4*)&su.at.part[wvx][512 + lane * 8] = v2;
          *(f32x4*)&su.at.part[wvx][512 + lane * 8 + 4] = v3;
        }
      }
      __syncthreads();
      {
        float rD = su.at.rd;
        for (int d = tid; d < D_; d += 512) {
          float s = 0.f;
          #pragma unroll
          for (int w = 0; w < 8; ++w) s += su.at.part[w][d];
          st_bypass_u16(ctxB + b_at * D_ + d, f2b(s * rD));
        }
      }
    } else {
      // stage hT2 (bf16) -> LDS chunks [kc][b]
      {
        const int b0 = tid & 31, kc0 = tid >> 5;
        const u16* hp = hT2 + b0 * H_;
        u32x4 v0, v1, v2, v3;
        ld4_bypass(hp + kc0 * 8, hp + (kc0 + 16) * 8,
                   hp + (kc0 + 32) * 8, hp + (kc0 + 48) * 8, v0, v1, v2, v3);
        su.g1.hst[(kc0     ) * 32 + b0] = v0;
        su.g1.hst[(kc0 + 16) * 32 + b0] = v1;
        su.g1.hst[(kc0 + 32) * 32 + b0] = v2;
        su.g1.hst[(kc0 + 48) * 32 + b0] = v3;
      }
      __syncthreads();
      #pragma unroll
      for (int c2 = 0; c2 < 2; ++c2) {
        int colidx = wvx * 2 + c2;
        int col = (colidx >> 2) * H_ + hbase + (colidx & 3);
        const u16* wp = WhhT + (size_t)col * H_ + p_ * 256;
        float a = 0.f;
        #pragma unroll 4
        for (int k8 = 0; k8 < 32; ++k8) {
          short8 w = *(const short8*)(wp + k8 * 8);
          short8 h8 = *(const short8*)&su.g1.hst[(p_ * 32 + k8) * 32 + bb_];
          #pragma unroll
          for (int j = 0; j < 8; ++j) a += b2f((u16)w[j]) * b2f((u16)h8[j]);
        }
        a += __shfl_xor(a, 32, 64);
        if (p_ == 0) {
          float ge = b2f(g_emb[((size_t)t * G4H + col) * 32 + bb_]);
          g1l[colidx][bb_] = a + ge;
        }
      }
    }
    tgt += NBLK;
    gridbar(bars, rel, bid, tgt);

    // ================= Phase 2 (gate blocks) =================
    if (!is_attn) {
      // stage ctx (bf16) -> LDS chunks [kc][b]
      {
        const int b0 = tid & 31, kc0 = tid >> 5;
        const u16* cp = ctxB + b0 * D_;
        u32x4 w0, w1, w2, w3, w4, w5;
        ld6_bypass(cp + kc0 * 8, cp + (kc0 + 16) * 8, cp + (kc0 + 32) * 8,
                   cp + (kc0 + 48) * 8, cp + (kc0 + 64) * 8, cp + (kc0 + 80) * 8,
                   w0, w1, w2, w3, w4, w5);
        su.g2.ctx[(kc0     ) * 32 + b0] = w0;
        su.g2.ctx[(kc0 + 16) * 32 + b0] = w1;
        su.g2.ctx[(kc0 + 32) * 32 + b0] = w2;
        su.g2.ctx[(kc0 + 48) * 32 + b0] = w3;
        su.g2.ctx[(kc0 + 64) * 32 + b0] = w4;
        su.g2.ctx[(kc0 + 80) * 32 + b0] = w5;
      }
      __syncthreads();
      #pragma unroll
      for (int c2 = 0; c2 < 2; ++c2) {
        int colidx = wvx * 2 + c2;
        int col = (colidx >> 2) * H_ + hbase + (colidx & 3);
        const u16* wp = WihDT + (size_t)col * D_ + p_ * 384;
        float a = 0.f;
        #pragma unroll 4
        for (int i = 0; i < 48; ++i) {
          short8 w = *(const short8*)(wp + i * 8);
          short8 cx = *(const short8*)&su.g2.ctx[(p_ * 48 + i) * 32 + bb_];
          #pragma unroll
          for (int j = 0; j < 8; ++j) a += b2f((u16)w[j]) * b2f((u16)cx[j]);
        }
        a += __shfl_xor(a, 32, 64);
        if (p_ == 0) gpre[colidx][bb_] = a + g1l[colidx][bb_];
      }
      __syncthreads();
      if (tid < 128) {
        int bb = tid & 31, j2 = tid >> 5;
        int hidx = hbase + j2;
        float gI = gpre[j2][bb], gF = gpre[4 + j2][bb];
        float gG = gpre[8 + j2][bb], gO = gpre[12 + j2][bb];
        float co = cfl[j2][bb];
        float cn = sigm(gF) * co + sigm(gI) * fast_tanh(gG);
        float hn = sigm(gO) * fast_tanh(cn);
        cfl[j2][bb] = cn;
        st_bypass_f32(hT + bb * H_ + hidx, hn);
        st_bypass_u16(hT2 + bb * H_ + hidx, f2b(hn));
        st_bypass_u16(h_hist + ((size_t)bb * T_ + t) * H_ + hidx, f2b(hn));
        if (t == T_ - 1) {
          out_h[bb * H_ + hidx] = hn;
          out_c[bb * H_ + hidx] = cn;
        }
      }
    }
    tgt += NBLK;
    gridbar(bars, rel, bid, tgt);
  }
}

extern "C" void kernel_launch(void* const* d_in, const int* in_sizes, int n_in,
                              void* d_out, int out_size, void* d_ws, size_t ws_size,
                              hipStream_t stream) {
  const int*   x    = (const int*)d_in[0];
  const float* enc  = (const float*)d_in[1];
  const int*   mask = (const int*)d_in[2];
  const float* emb  = (const float*)d_in[3];
  const float* We   = (const float*)d_in[4];
  const float* Wh   = (const float*)d_in[5];
  const float* v    = (const float*)d_in[6];
  const float* Wih  = (const float*)d_in[7];
  const float* Whh  = (const float*)d_in[8];
  const float* bih  = (const float*)d_in[9];
  const float* bhh  = (const float*)d_in[10];
  const float* fcW  = (const float*)d_in[11];
  const float* fcb  = (const float*)d_in[12];
  const float* W2h  = (const float*)d_in[13];
  const float* b2h  = (const float*)d_in[14];
  const float* W2c  = (const float*)d_in[15];
  const float* b2c  = (const float*)d_in[16];
  float* out = (float*)d_out;

  char* ws = (char*)d_ws;
  u16* enc_bf = (u16*)(ws + O_ENCBF);
  u16* Whbf   = (u16*)(ws + O_WHBFR);
  u16* WhhT   = (u16*)(ws + O_WHHT);
  u16* WihDT  = (u16*)(ws + O_WIHDT);
  u16* Ke     = (u16*)(ws + O_KE);
  u16* g_emb  = (u16*)(ws + O_GEMB);
  float* bsum = (float*)(ws + O_BSUM);
  float* hT   = (float*)(ws + O_HT);
  float* cT   = (float*)(ws + O_CT);
  u16* ctxB   = (u16*)(ws + O_CTX);
  u16* h_hist = (u16*)(ws + O_HIST);
  unsigned* bars = (unsigned*)(ws + O_BARS);
  u16* hT2    = (u16*)(ws + O_HT2);
  unsigned* rel = (unsigned*)(ws + O_REL);

  hipMemsetAsync(bars, 0, 2048, stream);
  hipMemsetAsync(rel, 0, 20480, stream);
  conv_bf<<<1024, 256, 0, stream>>>(enc, enc_bf, B_ * N_ * D_);
  conv_bf<<<256, 256, 0, stream>>>(Wh, Whbf, H_ * H_);
  transpose_bf<<<dim3(32, 8), 256, 0, stream>>>(Whh, WhhT, H_, G4H);
  transpose_bf<<<dim3(32, 12), 256, 0, stream>>>(Wih + (size_t)E_ * G4H, WihDT, D_, G4H);
  bsum_k<<<8, 256, 0, stream>>>(bih, bhh, bsum, G4H);
  init_hc<<<32, 512, 0, stream>>>(enc, W2h, b2h, W2c, b2c, hT, cT, hT2);
  // Ke = enc_bf @ We   (6272 x 512, K=768) -> bf16 row-major
  gemm2<0, 1, 0><<<dim3(4, 49), 256, 0, stream>>>(enc_bf, We, nullptr, (void*)Ke,
                                                  nullptr, B_ * N_, H_, D_, D_);
  // g_emb[t][col][b] = emb[x] @ Wih[:256] + bih + bhh  (4096 x 2048, K=256)
  gemm2<1, 3, 1><<<dim3(16, 32), 256, 0, stream>>>(emb, Wih, x, (void*)g_emb,
                                                   bsum, B_ * T_, G4H, E_, E_);
  recur3<<<NBLK, 512, 0, stream>>>(enc_bf, mask, Ke, Whbf, v, WhhT, WihDT, g_emb,
                                   cT, hT, hT2, ctxB, h_hist,
                                   out + (size_t)B_ * T_ * V_,
                                   out + (size_t)B_ * T_ * V_ + B_ * H_, bars, rel);
  // logits = h_hist @ fcW + fcb  (4096 x 10000, K=512) -> f32
  gemm2<0, 0, 1><<<dim3(79, 32), 256, 0, stream>>>(h_hist, fcW, nullptr, (void*)out,
                                                   fcb, B_ * T_, V_, H_, H_);
}

// Round 7
// 6020.638 us; speedup vs baseline: 4.4049x; 1.2625x over previous
//
#include <hip/hip_runtime.h>

typedef unsigned short u16;
typedef __attribute__((ext_vector_type(8))) short short8;
typedef __attribute__((ext_vector_type(4))) float f32x4;
typedef __attribute__((ext_vector_type(4))) unsigned int u32x4;

#define B_  32
#define T_  128
#define N_  196
#define D_  768
#define E_  256
#define H_  512
#define V_  10000
#define G4H 2048

// workspace offsets (bytes), all 256-aligned
#define O_ENCBF 0UL            // 9,633,792   enc bf16 [32][196][768]
#define O_WHBFR 9633792UL      // 524,288     Wh bf16 row-major [k][col]
#define O_WHHT  10158080UL     // 2,097,152   WhhT [2048 col][512 k]
#define O_WIHDT 12255232UL     // 3,145,728   WihDT[2048 col][768 d]
#define O_KE    15400960UL     // 6,422,528   Ke bf16 [6272][512]
#define O_GEMB  21823488UL     // 16,777,216  g_emb bf16 [128 t][2048 col][32 b]
#define O_BSUM  38600704UL     // 8,192       bih+bhh
#define O_HT    38608896UL     // 65,536      h f32 [32][512]
#define O_CT    38674432UL     // 65,536      c  f32 [32][512]
#define O_CTX   38739968UL     // 49,152      ctx bf16 [32][768]
#define O_HIST  38789120UL     // 4,194,304   h_hist bf16 [32*128][512]
#define O_HT2   42985472UL     // 32,768      h bf16 [32][512]

__device__ __forceinline__ float b2f(u16 u) {
  union { unsigned i; float f; } c; c.i = ((unsigned)u) << 16; return c.f;
}
__device__ __forceinline__ u16 f2b(float f) {   // RNE f32->bf16
  unsigned u = __float_as_uint(f);
  unsigned r = (u + 0x7fffu + ((u >> 16) & 1u)) >> 16;
  return (u16)r;
}
__device__ __forceinline__ float fast_tanh(float x) {
  float e = __expf(2.f * x);
  return 1.f - 2.f * __builtin_amdgcn_rcpf(e + 1.f);
}
__device__ __forceinline__ float sigm(float x) {
  return __builtin_amdgcn_rcpf(1.f + __expf(-x));
}
__device__ __forceinline__ float wred_sum(float x) {
  #pragma unroll
  for (int o = 32; o; o >>= 1) x += __shfl_xor(x, o, 64);
  return x;
}
__device__ __forceinline__ float wred_max(float x) {
  #pragma unroll
  for (int o = 32; o; o >>= 1) x = fmaxf(x, __shfl_xor(x, o, 64));
  return x;
}

// ---------------- prep kernels ----------------

__global__ void conv_bf(const float* __restrict__ in, u16* __restrict__ out, int n) {
  int i = blockIdx.x * blockDim.x + threadIdx.x;
  int st = gridDim.x * blockDim.x;
  for (; i < n; i += st) out[i] = f2b(in[i]);
}

__global__ void bsum_k(const float* __restrict__ a, const float* __restrict__ b,
                       float* __restrict__ o, int n) {
  int i = blockIdx.x * blockDim.x + threadIdx.x;
  if (i < n) o[i] = a[i] + b[i];
}

// out[c][r] = bf16(in[r][c]); in is R x C
__global__ void transpose_bf(const float* __restrict__ in, u16* __restrict__ out, int R, int C) {
  __shared__ float tl[64][65];
  int tid = threadIdx.x;
  int tc0 = blockIdx.x * 64, tr0 = blockIdx.y * 64;
  int cc = tid & 63;
  for (int rr = tid >> 6; rr < 64; rr += 4) {
    int rg = tr0 + rr, cg = tc0 + cc;
    tl[rr][cc] = (rg < R && cg < C) ? in[(size_t)rg * C + cg] : 0.f;
  }
  __syncthreads();
  int rr = tid & 63;
  for (int c2 = tid >> 6; c2 < 64; c2 += 4) {
    int cg = tc0 + c2, rg = tr0 + rr;
    if (cg < C && rg < R) out[(size_t)cg * R + rg] = f2b(tl[rr][c2]);
  }
}

// h0/c0 into [b][h] layout (+ bf16 mirror of h0)
__global__ __launch_bounds__(512) void init_hc(
    const float* __restrict__ enc, const float* __restrict__ W2h,
    const float* __restrict__ b2h, const float* __restrict__ W2c,
    const float* __restrict__ b2c, float* __restrict__ hT, float* __restrict__ cT,
    u16* __restrict__ hT2)
{
  __shared__ float pool[D_];
  int b = blockIdx.x, tid = threadIdx.x;
  for (int d = tid; d < D_; d += 512) {
    float s = 0.f;
    const float* ep = enc + (size_t)b * N_ * D_ + d;
    for (int n = 0; n < N_; ++n) s += ep[(size_t)n * D_];
    pool[d] = s * (1.f / 196.f);
  }
  __syncthreads();
  float a = b2h[tid], a2 = b2c[tid];
  #pragma unroll 4
  for (int d = 0; d < D_; ++d) {
    float pv = pool[d];
    a  += pv * W2h[d * H_ + tid];
    a2 += pv * W2c[d * H_ + tid];
  }
  float h0 = fast_tanh(a);
  hT[b * H_ + tid] = h0;
  hT2[b * H_ + tid] = f2b(h0);
  cT[b * H_ + tid] = fast_tanh(a2);
}

// ---------------- MFMA GEMM, B given as f32 K x N row-major (converted in-stage) ----
// AMODE: 0 = A bf16 [M][lda];  1 = A f32 with row gather via xidx (emb table)
// OUTMODE: 0 = f32 row-major; 1 = bf16 row-major; 3 = bf16 scatter [t][col][b]
template<int AMODE, int OUTMODE, int BIAS>
__global__ __launch_bounds__(256) void gemm2(
    const void* __restrict__ Av, const float* __restrict__ Bf,
    const int* __restrict__ xidx, void* __restrict__ Cv,
    const float* __restrict__ bias, int M, int N, int K, int lda)
{
  __shared__ __align__(16) u16 Al[128][72];
  __shared__ __align__(16) u16 Bl[128][72];
  const int tid = threadIdx.x;
  const int tm0 = blockIdx.y * 128, tn0 = blockIdx.x * 128;
  const int wv = tid >> 6, lane = tid & 63;
  const int wr = wv >> 1, wc = wv & 1;
  f32x4 acc[4][4] = {};
  const int r = tid >> 1, cb = (tid & 1) * 32;
  const int bkr = tid >> 5;          // 0..7
  const int bnc = (tid & 31) * 4;    // 0..124
  for (int k0 = 0; k0 < K; k0 += 64) {
    int rm = tm0 + r; if (rm >= M) rm = M - 1;
    if (AMODE == 0) {
      const u16* gp = (const u16*)Av + (size_t)rm * lda + k0 + cb;
      #pragma unroll
      for (int u = 0; u < 4; ++u)
        *(short8*)&Al[r][cb + u * 8] = *(const short8*)(gp + u * 8);
    } else {
      const float* gp = (const float*)Av + (size_t)xidx[rm] * lda + k0 + cb;
      #pragma unroll
      for (int u = 0; u < 4; ++u) {
        f32x4 a0 = *(const f32x4*)(gp + u * 8);
        f32x4 a1 = *(const f32x4*)(gp + u * 8 + 4);
        Al[r][cb + u * 8 + 0] = f2b(a0[0]); Al[r][cb + u * 8 + 1] = f2b(a0[1]);
        Al[r][cb + u * 8 + 2] = f2b(a0[2]); Al[r][cb + u * 8 + 3] = f2b(a0[3]);
        Al[r][cb + u * 8 + 4] = f2b(a1[0]); Al[r][cb + u * 8 + 5] = f2b(a1[1]);
        Al[r][cb + u * 8 + 6] = f2b(a1[2]); Al[r][cb + u * 8 + 7] = f2b(a1[3]);
      }
    }
    {
      int ncc = tn0 + bnc; if (ncc > N - 4) ncc = N - 4;
      #pragma unroll
      for (int u = 0; u < 8; ++u) {
        int kr = bkr + u * 8;
        const float* bp = Bf + (size_t)(k0 + kr) * N + ncc;
        f32x4 bv = *(const f32x4*)bp;
        #pragma unroll
        for (int j = 0; j < 4; ++j) Bl[bnc + j][kr] = f2b(bv[j]);
      }
    }
    __syncthreads();
    #pragma unroll
    for (int kk = 0; kk < 64; kk += 32) {
      short8 af[4], bfv[4];
      #pragma unroll
      for (int i = 0; i < 4; ++i)
        af[i] = *(const short8*)&Al[wr * 64 + i * 16 + (lane & 15)][kk + (lane >> 4) * 8];
      #pragma unroll
      for (int j = 0; j < 4; ++j)
        bfv[j] = *(const short8*)&Bl[wc * 64 + j * 16 + (lane & 15)][kk + (lane >> 4) * 8];
      #pragma unroll
      for (int i = 0; i < 4; ++i)
        #pragma unroll
        for (int j = 0; j < 4; ++j)
          acc[i][j] = __builtin_amdgcn_mfma_f32_16x16x32_bf16(af[i], bfv[j], acc[i][j], 0, 0, 0);
    }
    __syncthreads();
  }
  #pragma unroll
  for (int i = 0; i < 4; ++i) {
    int row0 = tm0 + wr * 64 + i * 16 + (lane >> 4) * 4;
    #pragma unroll
    for (int j = 0; j < 4; ++j) {
      int col = tn0 + wc * 64 + j * 16 + (lane & 15);
      if (col < N) {
        float bs = BIAS ? bias[col] : 0.f;
        #pragma unroll
        for (int rr2 = 0; rr2 < 4; ++rr2) {
          int row = row0 + rr2;
          if (row < M) {
            float val = acc[i][j][rr2] + bs;
            if (OUTMODE == 0) ((float*)Cv)[(size_t)row * N + col] = val;
            else if (OUTMODE == 1) ((u16*)Cv)[(size_t)row * N + col] = f2b(val);
            else {
              int tt = row & 127, bb = row >> 7;
              ((u16*)Cv)[((size_t)tt * G4H + col) * 32 + bb] = f2b(val);
            }
          }
        }
      }
    }
  }
}

// ---------------- per-step kernel A: attention ----------------
// 32 blocks x 512 (1 per batch). Reads h (f32), writes ctx (bf16).
__global__ __launch_bounds__(512) void attn_step(
    int t, const u16* __restrict__ enc_bf, const int* __restrict__ mask,
    const u16* __restrict__ Ke, const u16* __restrict__ Whbf,
    const float* __restrict__ vvec, const float* __restrict__ hT,
    u16* __restrict__ ctxB)
{
  __shared__ float h_l[512];
  __shared__ float hw8[512];       // [j][64]: hw8[(col&7)*64 + (col>>3)]
  __shared__ float sl[256];
  __shared__ float maskadd[256];
  __shared__ float part[8][768];
  __shared__ float rdv;

  const int b_at = blockIdx.x, tid = threadIdx.x;
  const int lane = tid & 63, wvx = tid >> 6;

  float vreg[8];
  #pragma unroll
  for (int j = 0; j < 8; ++j) vreg[j] = vvec[lane * 8 + j];
  for (int nn = tid; nn < N_; nn += 512)
    maskadd[nn] = (mask[b_at * N_ + nn] == 0) ? -1e9f : 0.f;
  h_l[tid] = hT[b_at * H_ + tid];
  __syncthreads();

  // hw[col] = sum_k h[k]*Wh[k][col]; lane owns 8 cols, waves split k
  {
    float acc8[8] = {0,0,0,0,0,0,0,0};
    #pragma unroll 4
    for (int kk = 0; kk < 64; ++kk) {
      int k = wvx * 64 + kk;
      float hk = h_l[k];
      short8 w = *(const short8*)(Whbf + (size_t)k * H_ + lane * 8);
      #pragma unroll
      for (int j = 0; j < 8; ++j) acc8[j] += hk * b2f((u16)w[j]);
    }
    f32x4 v0 = {acc8[0], acc8[1], acc8[2], acc8[3]};
    f32x4 v1 = {acc8[4], acc8[5], acc8[6], acc8[7]};
    *(f32x4*)&part[wvx][lane * 8] = v0;
    *(f32x4*)&part[wvx][lane * 8 + 4] = v1;
  }
  __syncthreads();
  {
    float s = 0.f;
    #pragma unroll
    for (int w = 0; w < 8; ++w) s += part[w][tid];
    hw8[(tid & 7) * 64 + (tid >> 3)] = s;
  }
  __syncthreads();
  // scores: full-wave reduction; lane covers Ke[n][lane*8..lane*8+7]
  for (int nn = wvx; nn < N_; nn += 8) {
    short8 kv = *(const short8*)(Ke + ((size_t)(b_at * N_ + nn)) * H_ + lane * 8);
    float p = 0.f;
    #pragma unroll
    for (int j = 0; j < 8; ++j)
      p += vreg[j] * fast_tanh(hw8[j * 64 + lane] + b2f((u16)kv[j]));
    p = wred_sum(p);
    if (lane == 0) sl[nn] = p + maskadd[nn];
  }
  __syncthreads();
  // softmax stats (wave 0), exp in place
  if (wvx == 0) {
    float m = -3.4e38f;
    for (int nn = lane; nn < N_; nn += 64) m = fmaxf(m, sl[nn]);
    m = wred_max(m);
    float s = 0.f;
    for (int nn = lane; nn < N_; nn += 64) {
      float e = __expf(sl[nn] - m);
      sl[nn] = e; s += e;
    }
    s = wred_sum(s);
    if (lane == 0) rdv = 1.f / s;
  }
  __syncthreads();
  // context partials (coalesced short8 enc reads)
  {
    float acc0[8] = {0,0,0,0,0,0,0,0}, acc1[8] = {0,0,0,0,0,0,0,0};
    for (int nn = wvx; nn < N_; nn += 8) {
      float al = sl[nn];
      const u16* ep = enc_bf + ((size_t)(b_at * N_ + nn)) * D_;
      short8 e0 = *(const short8*)(ep + lane * 8);
      #pragma unroll
      for (int j = 0; j < 8; ++j) acc0[j] += al * b2f((u16)e0[j]);
      if (lane < 32) {
        short8 e1 = *(const short8*)(ep + 512 + lane * 8);
        #pragma unroll
        for (int j = 0; j < 8; ++j) acc1[j] += al * b2f((u16)e1[j]);
      }
    }
    f32x4 v0 = {acc0[0], acc0[1], acc0[2], acc0[3]};
    f32x4 v1 = {acc0[4], acc0[5], acc0[6], acc0[7]};
    *(f32x4*)&part[wvx][lane * 8] = v0;
    *(f32x4*)&part[wvx][lane * 8 + 4] = v1;
    if (lane < 32) {
      f32x4 v2 = {acc1[0], acc1[1], acc1[2], acc1[3]};
      f32x4 v3 = {acc1[4], acc1[5], acc1[6], acc1[7]};
      *(f32x4*)&part[wvx][512 + lane * 8] = v2;
      *(f32x4*)&part[wvx][512 + lane * 8 + 4] = v3;
    }
  }
  __syncthreads();
  {
    float rD = rdv;
    for (int d = tid; d < D_; d += 512) {
      float s = 0.f;
      #pragma unroll
      for (int w = 0; w < 8; ++w) s += part[w][d];
      ctxB[b_at * D_ + d] = f2b(s * rD);
    }
  }
}

// ---------------- per-step kernel B: gates + pointwise ----------------
// 256 blocks x 512; block gi owns h-indices gi*2, gi*2+1 (8 gate cols, 1/wave).
__global__ __launch_bounds__(512) void gate_step(
    int t, const u16* __restrict__ WhhT, const u16* __restrict__ WihDT,
    const u16* __restrict__ g_emb, const u16* __restrict__ ctxB,
    float* __restrict__ hT, u16* __restrict__ hT2, float* __restrict__ cT,
    u16* __restrict__ h_hist, float* __restrict__ out_h, float* __restrict__ out_c)
{
  __shared__ u32x4 hst[64 * 32];    // h bf16 chunks [kc][b], 32KB
  __shared__ u32x4 ctx[96 * 32];    // ctx bf16 chunks [kc][b], 48KB
  __shared__ float g1l[8][32];
  __shared__ float gpre[8][32];

  const int gi = blockIdx.x, tid = threadIdx.x;
  const int lane = tid & 63, wvx = tid >> 6;
  const int hbase = gi * 2;
  const int p_ = lane >> 5, bb_ = lane & 31;

  // stage hT2 and ctx (bf16) -> LDS chunks [kc][b]
  {
    const int b0 = tid & 31, kc0 = tid >> 5;
    const u16* hp = hT2 + b0 * H_;
    hst[(kc0     ) * 32 + b0] = *(const u32x4*)(hp + kc0 * 8);
    hst[(kc0 + 16) * 32 + b0] = *(const u32x4*)(hp + (kc0 + 16) * 8);
    hst[(kc0 + 32) * 32 + b0] = *(const u32x4*)(hp + (kc0 + 32) * 8);
    hst[(kc0 + 48) * 32 + b0] = *(const u32x4*)(hp + (kc0 + 48) * 8);
    const u16* cp = ctxB + b0 * D_;
    ctx[(kc0     ) * 32 + b0] = *(const u32x4*)(cp + kc0 * 8);
    ctx[(kc0 + 16) * 32 + b0] = *(const u32x4*)(cp + (kc0 + 16) * 8);
    ctx[(kc0 + 32) * 32 + b0] = *(const u32x4*)(cp + (kc0 + 32) * 8);
    ctx[(kc0 + 48) * 32 + b0] = *(const u32x4*)(cp + (kc0 + 48) * 8);
    ctx[(kc0 + 64) * 32 + b0] = *(const u32x4*)(cp + (kc0 + 64) * 8);
    ctx[(kc0 + 80) * 32 + b0] = *(const u32x4*)(cp + (kc0 + 80) * 8);
  }
  __syncthreads();

  const int q = wvx >> 1, jj = wvx & 1;
  const int col = q * H_ + hbase + jj;
  // g1 = Whh[:,col] . h + g_emb
  {
    const u16* wp = WhhT + (size_t)col * H_ + p_ * 256;
    float a = 0.f;
    #pragma unroll 4
    for (int k8 = 0; k8 < 32; ++k8) {
      short8 w = *(const short8*)(wp + k8 * 8);
      short8 h8 = *(const short8*)&hst[(p_ * 32 + k8) * 32 + bb_];
      #pragma unroll
      for (int j = 0; j < 8; ++j) a += b2f((u16)w[j]) * b2f((u16)h8[j]);
    }
    a += __shfl_xor(a, 32, 64);
    if (p_ == 0) {
      float ge = b2f(g_emb[((size_t)t * G4H + col) * 32 + bb_]);
      g1l[wvx][bb_] = a + ge;
    }
  }
  // g2 = WihD[:,col] . ctx
  {
    const u16* wp = WihDT + (size_t)col * D_ + p_ * 384;
    float a = 0.f;
    #pragma unroll 4
    for (int i = 0; i < 48; ++i) {
      short8 w = *(const short8*)(wp + i * 8);
      short8 cx = *(const short8*)&ctx[(p_ * 48 + i) * 32 + bb_];
      #pragma unroll
      for (int j = 0; j < 8; ++j) a += b2f((u16)w[j]) * b2f((u16)cx[j]);
    }
    a += __shfl_xor(a, 32, 64);
    if (p_ == 0) gpre[wvx][bb_] = a + g1l[wvx][bb_];
  }
  __syncthreads();
  if (tid < 64) {
    int bb = tid & 31, j2 = tid >> 5;
    int hidx = hbase + j2;
    float gI = gpre[j2][bb], gF = gpre[2 + j2][bb];
    float gG = gpre[4 + j2][bb], gO = gpre[6 + j2][bb];
    float co = cT[bb * H_ + hidx];
    float cn = sigm(gF) * co + sigm(gI) * fast_tanh(gG);
    float hn = sigm(gO) * fast_tanh(cn);
    cT[bb * H_ + hidx] = cn;
    hT[bb * H_ + hidx] = hn;
    hT2[bb * H_ + hidx] = f2b(hn);
    h_hist[((size_t)bb * T_ + t) * H_ + hidx] = f2b(hn);
    if (t == T_ - 1) {
      out_h[bb * H_ + hidx] = hn;
      out_c[bb * H_ + hidx] = cn;
    }
  }
}

extern "C" void kernel_launch(void* const* d_in, const int* in_sizes, int n_in,
                              void* d_out, int out_size, void* d_ws, size_t ws_size,
                              hipStream_t stream) {
  const int*   x    = (const int*)d_in[0];
  const float* enc  = (const float*)d_in[1];
  const int*   mask = (const int*)d_in[2];
  const float* emb  = (const float*)d_in[3];
  const float* We   = (const float*)d_in[4];
  const float* Wh   = (const float*)d_in[5];
  const float* v    = (const float*)d_in[6];
  const float* Wih  = (const float*)d_in[7];
  const float* Whh  = (const float*)d_in[8];
  const float* bih  = (const float*)d_in[9];
  const float* bhh  = (const float*)d_in[10];
  const float* fcW  = (const float*)d_in[11];
  const float* fcb  = (const float*)d_in[12];
  const float* W2h  = (const float*)d_in[13];
  const float* b2h  = (const float*)d_in[14];
  const float* W2c  = (const float*)d_in[15];
  const float* b2c  = (const float*)d_in[16];
  float* out = (float*)d_out;

  char* ws = (char*)d_ws;
  u16* enc_bf = (u16*)(ws + O_ENCBF);
  u16* Whbf   = (u16*)(ws + O_WHBFR);
  u16* WhhT   = (u16*)(ws + O_WHHT);
  u16* WihDT  = (u16*)(ws + O_WIHDT);
  u16* Ke     = (u16*)(ws + O_KE);
  u16* g_emb  = (u16*)(ws + O_GEMB);
  float* bsum = (float*)(ws + O_BSUM);
  float* hT   = (float*)(ws + O_HT);
  float* cT   = (float*)(ws + O_CT);
  u16* ctxB   = (u16*)(ws + O_CTX);
  u16* h_hist = (u16*)(ws + O_HIST);
  u16* hT2    = (u16*)(ws + O_HT2);
  float* out_h = out + (size_t)B_ * T_ * V_;
  float* out_c = out_h + B_ * H_;

  conv_bf<<<1024, 256, 0, stream>>>(enc, enc_bf, B_ * N_ * D_);
  conv_bf<<<256, 256, 0, stream>>>(Wh, Whbf, H_ * H_);
  transpose_bf<<<dim3(32, 8), 256, 0, stream>>>(Whh, WhhT, H_, G4H);
  transpose_bf<<<dim3(32, 12), 256, 0, stream>>>(Wih + (size_t)E_ * G4H, WihDT, D_, G4H);
  bsum_k<<<8, 256, 0, stream>>>(bih, bhh, bsum, G4H);
  init_hc<<<32, 512, 0, stream>>>(enc, W2h, b2h, W2c, b2c, hT, cT, hT2);
  // Ke = enc_bf @ We   (6272 x 512, K=768) -> bf16 row-major
  gemm2<0, 1, 0><<<dim3(4, 49), 256, 0, stream>>>(enc_bf, We, nullptr, (void*)Ke,
                                                  nullptr, B_ * N_, H_, D_, D_);
  // g_emb[t][col][b] = emb[x] @ Wih[:256] + bih + bhh  (4096 x 2048, K=256)
  gemm2<1, 3, 1><<<dim3(16, 32), 256, 0, stream>>>(emb, Wih, x, (void*)g_emb,
                                                   bsum, B_ * T_, G4H, E_, E_);
  for (int t = 0; t < T_; ++t) {
    attn_step<<<32, 512, 0, stream>>>(t, enc_bf, mask, Ke, Whbf, v, hT, ctxB);
    gate_step<<<256, 512, 0, stream>>>(t, WhhT, WihDT, g_emb, ctxB,
                                       hT, hT2, cT, h_hist, out_h, out_c);
  }
  // logits = h_hist @ fcW + fcb  (4096 x 10000, K=512) -> f32
  gemm2<0, 0, 1><<<dim3(79, 32), 256, 0, stream>>>(h_hist, fcW, nullptr, (void*)out,
                                                   fcb, B_ * T_, V_, H_, H_);
}

// Round 8
// 5546.114 us; speedup vs baseline: 4.7817x; 1.0856x over previous
//
#include <hip/hip_runtime.h>

typedef unsigned short u16;
typedef __attribute__((ext_vector_type(8))) short short8;
typedef __attribute__((ext_vector_type(4))) float f32x4;
typedef __attribute__((ext_vector_type(4))) unsigned int u32x4;

#define B_  32
#define T_  128
#define N_  196
#define D_  768
#define E_  256
#define H_  512
#define V_  10000
#define G4H 2048

// workspace offsets (bytes), all 256-aligned
#define O_ENCBF 0UL            // 9,633,792   enc bf16 [32][196][768]
#define O_WHT   9633792UL      // 524,288     WhT bf16 [col][k]
#define O_WHHT  10158080UL     // 2,097,152   WhhT [2048 col][512 k]
#define O_WIHDT 12255232UL     // 3,145,728   WihDT[2048 col][768 d]
#define O_KE    15400960UL     // 6,422,528   Ke bf16 [6272][512]
#define O_GEMB  21823488UL     // 16,777,216  g_emb bf16 [128 t][2048 col][32 b]
#define O_BSUM  38600704UL     // 8,192       bih+bhh
#define O_HT    38608896UL     // 65,536      h f32 [32][512]
#define O_CT    38674432UL     // 65,536      c  f32 [32][512]
#define O_HIST  38789120UL     // 4,194,304   h_hist bf16 [32*128][512]
#define O_HT2   42983424UL     // 32,768      h bf16 [32][512]
#define O_HW    43016192UL     // 65,536      hw f32 [32][512]
#define O_CTXA  43081728UL     // 98,304      ctxAcc f32 [32][768]
#define O_DEN   43180032UL     // 512         denom f32 [32]

__device__ __forceinline__ float b2f(u16 u) {
  union { unsigned i; float f; } c; c.i = ((unsigned)u) << 16; return c.f;
}
__device__ __forceinline__ u16 f2b(float f) {   // RNE f32->bf16
  unsigned u = __float_as_uint(f);
  unsigned r = (u + 0x7fffu + ((u >> 16) & 1u)) >> 16;
  return (u16)r;
}
__device__ __forceinline__ float fast_tanh(float x) {
  float e = __expf(2.f * x);
  return 1.f - 2.f * __builtin_amdgcn_rcpf(e + 1.f);
}
__device__ __forceinline__ float sigm(float x) {
  return __builtin_amdgcn_rcpf(1.f + __expf(-x));
}
__device__ __forceinline__ float wred_sum(float x) {
  #pragma unroll
  for (int o = 32; o; o >>= 1) x += __shfl_xor(x, o, 64);
  return x;
}

// ---------------- prep kernels ----------------

__global__ void conv_bf(const float* __restrict__ in, u16* __restrict__ out, int n) {
  int i = blockIdx.x * blockDim.x + threadIdx.x;
  int st = gridDim.x * blockDim.x;
  for (; i < n; i += st) out[i] = f2b(in[i]);
}

__global__ void bsum_k(const float* __restrict__ a, const float* __restrict__ b,
                       float* __restrict__ o, int n) {
  int i = blockIdx.x * blockDim.x + threadIdx.x;
  if (i < n) o[i] = a[i] + b[i];
}

// out[c][r] = bf16(in[r][c]); in is R x C
__global__ void transpose_bf(const float* __restrict__ in, u16* __restrict__ out, int R, int C) {
  __shared__ float tl[64][65];
  int tid = threadIdx.x;
  int tc0 = blockIdx.x * 64, tr0 = blockIdx.y * 64;
  int cc = tid & 63;
  for (int rr = tid >> 6; rr < 64; rr += 4) {
    int rg = tr0 + rr, cg = tc0 + cc;
    tl[rr][cc] = (rg < R && cg < C) ? in[(size_t)rg * C + cg] : 0.f;
  }
  __syncthreads();
  int rr = tid & 63;
  for (int c2 = tid >> 6; c2 < 64; c2 += 4) {
    int cg = tc0 + c2, rg = tr0 + rr;
    if (cg < C && rg < R) out[(size_t)cg * R + rg] = f2b(tl[rr][c2]);
  }
}

// h0/c0 into [b][h] layout (+ bf16 mirror of h0)
__global__ __launch_bounds__(512) void init_hc(
    const float* __restrict__ enc, const float* __restrict__ W2h,
    const float* __restrict__ b2h, const float* __restrict__ W2c,
    const float* __restrict__ b2c, float* __restrict__ hT, float* __restrict__ cT,
    u16* __restrict__ hT2)
{
  __shared__ float pool[D_];
  int b = blockIdx.x, tid = threadIdx.x;
  for (int d = tid; d < D_; d += 512) {
    float s = 0.f;
    const float* ep = enc + (size_t)b * N_ * D_ + d;
    for (int n = 0; n < N_; ++n) s += ep[(size_t)n * D_];
    pool[d] = s * (1.f / 196.f);
  }
  __syncthreads();
  float a = b2h[tid], a2 = b2c[tid];
  #pragma unroll 4
  for (int d = 0; d < D_; ++d) {
    float pv = pool[d];
    a  += pv * W2h[d * H_ + tid];
    a2 += pv * W2c[d * H_ + tid];
  }
  float h0 = fast_tanh(a);
  hT[b * H_ + tid] = h0;
  hT2[b * H_ + tid] = f2b(h0);
  cT[b * H_ + tid] = fast_tanh(a2);
}

// ---------------- MFMA GEMM, B given as f32 K x N row-major (converted in-stage) ----
template<int AMODE, int OUTMODE, int BIAS>
__global__ __launch_bounds__(256) void gemm2(
    const void* __restrict__ Av, const float* __restrict__ Bf,
    const int* __restrict__ xidx, void* __restrict__ Cv,
    const float* __restrict__ bias, int M, int N, int K, int lda)
{
  __shared__ __align__(16) u16 Al[128][72];
  __shared__ __align__(16) u16 Bl[128][72];
  const int tid = threadIdx.x;
  const int tm0 = blockIdx.y * 128, tn0 = blockIdx.x * 128;
  const int wv = tid >> 6, lane = tid & 63;
  const int wr = wv >> 1, wc = wv & 1;
  f32x4 acc[4][4] = {};
  const int r = tid >> 1, cb = (tid & 1) * 32;
  const int bkr = tid >> 5;
  const int bnc = (tid & 31) * 4;
  for (int k0 = 0; k0 < K; k0 += 64) {
    int rm = tm0 + r; if (rm >= M) rm = M - 1;
    if (AMODE == 0) {
      const u16* gp = (const u16*)Av + (size_t)rm * lda + k0 + cb;
      #pragma unroll
      for (int u = 0; u < 4; ++u)
        *(short8*)&Al[r][cb + u * 8] = *(const short8*)(gp + u * 8);
    } else {
      const float* gp = (const float*)Av + (size_t)xidx[rm] * lda + k0 + cb;
      #pragma unroll
      for (int u = 0; u < 4; ++u) {
        f32x4 a0 = *(const f32x4*)(gp + u * 8);
        f32x4 a1 = *(const f32x4*)(gp + u * 8 + 4);
        Al[r][cb + u * 8 + 0] = f2b(a0[0]); Al[r][cb + u * 8 + 1] = f2b(a0[1]);
        Al[r][cb + u * 8 + 2] = f2b(a0[2]); Al[r][cb + u * 8 + 3] = f2b(a0[3]);
        Al[r][cb + u * 8 + 4] = f2b(a1[0]); Al[r][cb + u * 8 + 5] = f2b(a1[1]);
        Al[r][cb + u * 8 + 6] = f2b(a1[2]); Al[r][cb + u * 8 + 7] = f2b(a1[3]);
      }
    }
    {
      int ncc = tn0 + bnc; if (ncc > N - 4) ncc = N - 4;
      #pragma unroll
      for (int u = 0; u < 8; ++u) {
        int kr = bkr + u * 8;
        const float* bp = Bf + (size_t)(k0 + kr) * N + ncc;
        f32x4 bv = *(const f32x4*)bp;
        #pragma unroll
        for (int j = 0; j < 4; ++j) Bl[bnc + j][kr] = f2b(bv[j]);
      }
    }
    __syncthreads();
    #pragma unroll
    for (int kk = 0; kk < 64; kk += 32) {
      short8 af[4], bfv[4];
      #pragma unroll
      for (int i = 0; i < 4; ++i)
        af[i] = *(const short8*)&Al[wr * 64 + i * 16 + (lane & 15)][kk + (lane >> 4) * 8];
      #pragma unroll
      for (int j = 0; j < 4; ++j)
        bfv[j] = *(const short8*)&Bl[wc * 64 + j * 16 + (lane & 15)][kk + (lane >> 4) * 8];
      #pragma unroll
      for (int i = 0; i < 4; ++i)
        #pragma unroll
        for (int j = 0; j < 4; ++j)
          acc[i][j] = __builtin_amdgcn_mfma_f32_16x16x32_bf16(af[i], bfv[j], acc[i][j], 0, 0, 0);
    }
    __syncthreads();
  }
  #pragma unroll
  for (int i = 0; i < 4; ++i) {
    int row0 = tm0 + wr * 64 + i * 16 + (lane >> 4) * 4;
    #pragma unroll
    for (int j = 0; j < 4; ++j) {
      int col = tn0 + wc * 64 + j * 16 + (lane & 15);
      if (col < N) {
        float bs = BIAS ? bias[col] : 0.f;
        #pragma unroll
        for (int rr2 = 0; rr2 < 4; ++rr2) {
          int row = row0 + rr2;
          if (row < M) {
            float val = acc[i][j][rr2] + bs;
            if (OUTMODE == 0) ((float*)Cv)[(size_t)row * N + col] = val;
            else if (OUTMODE == 1) ((u16*)Cv)[(size_t)row * N + col] = f2b(val);
            else {
              int tt = row & 127, bb = row >> 7;
              ((u16*)Cv)[((size_t)tt * G4H + col) * 32 + bb] = f2b(val);
            }
          }
        }
      }
    }
  }
}

// ---------------- K1: hw = h @ Wh (column-split) + zero ctxAcc/denom ----------------
// 128 blocks x 128 thr; block g computes hw[:, g*4 .. g*4+3].
__global__ __launch_bounds__(128) void hw_step(
    const float* __restrict__ hT, const u16* __restrict__ WhT,
    float* __restrict__ hw, float* __restrict__ ctxAcc, float* __restrict__ denom)
{
  __shared__ f32x4 h_l[128 * 33];   // h chunks [kc][b], padded
  const int tid = threadIdx.x, g = blockIdx.x;
  // zero ctxAcc slice (24576/128 = 192 per block) + denom
  {
    int base = g * 192;
    ctxAcc[base + tid] = 0.f;
    if (tid < 64) ctxAcc[base + 128 + tid] = 0.f;
    if (g == 0 && tid < 32) denom[tid] = 0.f;
  }
  // stage h: 4096 chunks of f32x4, coalesced
  for (int idx = tid; idx < 4096; idx += 128) {
    int b = idx >> 7, kc = idx & 127;
    h_l[kc * 33 + b] = *(const f32x4*)(hT + b * H_ + kc * 4);
  }
  __syncthreads();
  const int b = tid & 31, c4 = tid >> 5;
  const int col = g * 4 + c4;
  const u16* wp = WhT + (size_t)col * H_;
  float acc = 0.f;
  #pragma unroll 4
  for (int k8 = 0; k8 < 64; ++k8) {
    short8 w = *(const short8*)(wp + k8 * 8);
    f32x4 ha = h_l[(2 * k8) * 33 + b];
    f32x4 hb = h_l[(2 * k8 + 1) * 33 + b];
    acc += b2f((u16)w[0]) * ha[0] + b2f((u16)w[1]) * ha[1]
         + b2f((u16)w[2]) * ha[2] + b2f((u16)w[3]) * ha[3]
         + b2f((u16)w[4]) * hb[0] + b2f((u16)w[5]) * hb[1]
         + b2f((u16)w[6]) * hb[2] + b2f((u16)w[7]) * hb[3];
  }
  hw[b * H_ + col] = acc;
}

// ---------------- K2: attention slice ----------------
// 256 blocks x 256 thr; block = (b, s): scores+exp for n in [s*25, s*25+25),
// atomic-add unnormalized context numerator + denom partial.
__global__ __launch_bounds__(256) void attn_slice(
    const u16* __restrict__ enc_bf, const int* __restrict__ mask,
    const u16* __restrict__ Ke, const float* __restrict__ vvec,
    const float* __restrict__ hw,
    float* __restrict__ ctxAcc, float* __restrict__ denom)
{
  __shared__ float hw8[512];   // swizzled: hw8[(c&7)*64 + (c>>3)] = hw[c]
  __shared__ float el[32];
  const int bs = blockIdx.x, tid = threadIdx.x;
  const int b = bs >> 3, s = bs & 7;
  const int n0 = s * 25;
  const int nmax = min(25, N_ - n0);
  const int lane = tid & 63, wv = tid >> 6;

  for (int c = tid; c < H_; c += 256)
    hw8[(c & 7) * 64 + (c >> 3)] = hw[b * H_ + c];
  __syncthreads();

  float vreg[8];
  #pragma unroll
  for (int j = 0; j < 8; ++j) vreg[j] = vvec[lane * 8 + j];

  // scores -> e (no max subtraction; |score| <= sum|v| ~ 9)
  for (int nn = wv; nn < nmax; nn += 4) {
    int n = n0 + nn;
    short8 kv = *(const short8*)(Ke + ((size_t)(b * N_ + n)) * H_ + lane * 8);
    float p = 0.f;
    #pragma unroll
    for (int j = 0; j < 8; ++j)
      p += vreg[j] * fast_tanh(hw8[j * 64 + lane] + b2f((u16)kv[j]));
    p = wred_sum(p);
    if (lane == 0)
      el[nn] = (mask[b * N_ + n] == 0) ? 0.f : __expf(p);
  }
  __syncthreads();
  // denom partial (wave 0)
  if (wv == 0) {
    float sp = (lane < nmax) ? el[lane] : 0.f;
    sp = wred_sum(sp);
    if (lane == 0) atomicAdd(denom + b, sp);
  }
  // context numerator: 3 coalesced d-passes
  float a0 = 0.f, a1 = 0.f, a2 = 0.f;
  for (int nn = 0; nn < nmax; ++nn) {
    float e = el[nn];
    const u16* ep = enc_bf + ((size_t)(b * N_ + n0 + nn)) * D_;
    a0 += e * b2f(ep[tid]);
    a1 += e * b2f(ep[tid + 256]);
    a2 += e * b2f(ep[tid + 512]);
  }
  float* cp = ctxAcc + b * D_;
  atomicAdd(cp + tid, a0);
  atomicAdd(cp + tid + 256, a1);
  atomicAdd(cp + tid + 512, a2);
}

// ---------------- K3: gates + pointwise ----------------
// 256 blocks x 512; block gi owns h-indices gi*2, gi*2+1 (8 gate cols, 1/wave).
__global__ __launch_bounds__(512) void gate_step(
    int t, const u16* __restrict__ WhhT, const u16* __restrict__ WihDT,
    const u16* __restrict__ g_emb, const float* __restrict__ ctxAcc,
    const float* __restrict__ denom,
    float* __restrict__ hT, u16* __restrict__ hT2, float* __restrict__ cT,
    u16* __restrict__ h_hist, float* __restrict__ out_h, float* __restrict__ out_c)
{
  __shared__ u32x4 hst[64 * 32];    // h bf16 chunks [kc][b], 32KB
  __shared__ u32x4 ctx[96 * 32];    // ctx bf16 chunks [kc][b], 48KB
  __shared__ float g1l[8][32];
  __shared__ float gpre[8][32];

  const int gi = blockIdx.x, tid = threadIdx.x;
  const int lane = tid & 63, wvx = tid >> 6;
  const int hbase = gi * 2;
  const int p_ = lane >> 5, bb_ = lane & 31;

  // stage hT2 (bf16) and ctxAcc (f32, scaled by 1/denom) -> LDS chunks [kc][b]
  {
    const int b0 = tid & 31, kc0 = tid >> 5;
    const u16* hp = hT2 + b0 * H_;
    hst[(kc0     ) * 32 + b0] = *(const u32x4*)(hp + kc0 * 8);
    hst[(kc0 + 16) * 32 + b0] = *(const u32x4*)(hp + (kc0 + 16) * 8);
    hst[(kc0 + 32) * 32 + b0] = *(const u32x4*)(hp + (kc0 + 32) * 8);
    hst[(kc0 + 48) * 32 + b0] = *(const u32x4*)(hp + (kc0 + 48) * 8);
    float rd = 1.f / denom[b0];
    const float* cp = ctxAcc + b0 * D_;
    #pragma unroll
    for (int r = 0; r < 6; ++r) {
      int kc = kc0 + r * 16;
      f32x4 x0 = *(const f32x4*)(cp + kc * 8);
      f32x4 x1 = *(const f32x4*)(cp + kc * 8 + 4);
      u32x4 pk;
      pk[0] = (unsigned)f2b(x0[0] * rd) | ((unsigned)f2b(x0[1] * rd) << 16);
      pk[1] = (unsigned)f2b(x0[2] * rd) | ((unsigned)f2b(x0[3] * rd) << 16);
      pk[2] = (unsigned)f2b(x1[0] * rd) | ((unsigned)f2b(x1[1] * rd) << 16);
      pk[3] = (unsigned)f2b(x1[2] * rd) | ((unsigned)f2b(x1[3] * rd) << 16);
      ctx[kc * 32 + b0] = pk;
    }
  }
  __syncthreads();

  const int q = wvx >> 1, jj = wvx & 1;
  const int col = q * H_ + hbase + jj;
  // g1 = Whh[:,col] . h + g_emb
  {
    const u16* wp = WhhT + (size_t)col * H_ + p_ * 256;
    float a = 0.f;
    #pragma unroll 4
    for (int k8 = 0; k8 < 32; ++k8) {
      short8 w = *(const short8*)(wp + k8 * 8);
      short8 h8 = *(const short8*)&hst[(p_ * 32 + k8) * 32 + bb_];
      #pragma unroll
      for (int j = 0; j < 8; ++j) a += b2f((u16)w[j]) * b2f((u16)h8[j]);
    }
    a += __shfl_xor(a, 32, 64);
    if (p_ == 0) {
      float ge = b2f(g_emb[((size_t)t * G4H + col) * 32 + bb_]);
      g1l[wvx][bb_] = a + ge;
    }
  }
  // g2 = WihD[:,col] . ctx
  {
    const u16* wp = WihDT + (size_t)col * D_ + p_ * 384;
    float a = 0.f;
    #pragma unroll 4
    for (int i = 0; i < 48; ++i) {
      short8 w = *(const short8*)(wp + i * 8);
      short8 cx = *(const short8*)&ctx[(p_ * 48 + i) * 32 + bb_];
      #pragma unroll
      for (int j = 0; j < 8; ++j) a += b2f((u16)w[j]) * b2f((u16)cx[j]);
    }
    a += __shfl_xor(a, 32, 64);
    if (p_ == 0) gpre[wvx][bb_] = a + g1l[wvx][bb_];
  }
  __syncthreads();
  if (tid < 64) {
    int bb = tid & 31, j2 = tid >> 5;
    int hidx = hbase + j2;
    float gI = gpre[j2][bb], gF = gpre[2 + j2][bb];
    float gG = gpre[4 + j2][bb], gO = gpre[6 + j2][bb];
    float co = cT[bb * H_ + hidx];
    float cn = sigm(gF) * co + sigm(gI) * fast_tanh(gG);
    float hn = sigm(gO) * fast_tanh(cn);
    cT[bb * H_ + hidx] = cn;
    hT[bb * H_ + hidx] = hn;
    hT2[bb * H_ + hidx] = f2b(hn);
    h_hist[((size_t)bb * T_ + t) * H_ + hidx] = f2b(hn);
    if (t == T_ - 1) {
      out_h[bb * H_ + hidx] = hn;
      out_c[bb * H_ + hidx] = cn;
    }
  }
}

extern "C" void kernel_launch(void* const* d_in, const int* in_sizes, int n_in,
                              void* d_out, int out_size, void* d_ws, size_t ws_size,
                              hipStream_t stream) {
  const int*   x    = (const int*)d_in[0];
  const float* enc  = (const float*)d_in[1];
  const int*   mask = (const int*)d_in[2];
  const float* emb  = (const float*)d_in[3];
  const float* We   = (const float*)d_in[4];
  const float* Wh   = (const float*)d_in[5];
  const float* v    = (const float*)d_in[6];
  const float* Wih  = (const float*)d_in[7];
  const float* Whh  = (const float*)d_in[8];
  const float* bih  = (const float*)d_in[9];
  const float* bhh  = (const float*)d_in[10];
  const float* fcW  = (const float*)d_in[11];
  const float* fcb  = (const float*)d_in[12];
  const float* W2h  = (const float*)d_in[13];
  const float* b2h  = (const float*)d_in[14];
  const float* W2c  = (const float*)d_in[15];
  const float* b2c  = (const float*)d_in[16];
  float* out = (float*)d_out;

  char* ws = (char*)d_ws;
  u16* enc_bf = (u16*)(ws + O_ENCBF);
  u16* WhT    = (u16*)(ws + O_WHT);
  u16* WhhT   = (u16*)(ws + O_WHHT);
  u16* WihDT  = (u16*)(ws + O_WIHDT);
  u16* Ke     = (u16*)(ws + O_KE);
  u16* g_emb  = (u16*)(ws + O_GEMB);
  float* bsum = (float*)(ws + O_BSUM);
  float* hT   = (float*)(ws + O_HT);
  float* cT   = (float*)(ws + O_CT);
  u16* h_hist = (u16*)(ws + O_HIST);
  u16* hT2    = (u16*)(ws + O_HT2);
  float* hw   = (float*)(ws + O_HW);
  float* ctxAcc = (float*)(ws + O_CTXA);
  float* denom  = (float*)(ws + O_DEN);
  float* out_h = out + (size_t)B_ * T_ * V_;
  float* out_c = out_h + B_ * H_;

  conv_bf<<<1024, 256, 0, stream>>>(enc, enc_bf, B_ * N_ * D_);
  transpose_bf<<<dim3(8, 8), 256, 0, stream>>>(Wh, WhT, H_, H_);
  transpose_bf<<<dim3(32, 8), 256, 0, stream>>>(Whh, WhhT, H_, G4H);
  transpose_bf<<<dim3(32, 12), 256, 0, stream>>>(Wih + (size_t)E_ * G4H, WihDT, D_, G4H);
  bsum_k<<<8, 256, 0, stream>>>(bih, bhh, bsum, G4H);
  init_hc<<<32, 512, 0, stream>>>(enc, W2h, b2h, W2c, b2c, hT, cT, hT2);
  // Ke = enc_bf @ We   (6272 x 512, K=768) -> bf16 row-major
  gemm2<0, 1, 0><<<dim3(4, 49), 256, 0, stream>>>(enc_bf, We, nullptr, (void*)Ke,
                                                  nullptr, B_ * N_, H_, D_, D_);
  // g_emb[t][col][b] = emb[x] @ Wih[:256] + bih + bhh  (4096 x 2048, K=256)
  gemm2<1, 3, 1><<<dim3(16, 32), 256, 0, stream>>>(emb, Wih, x, (void*)g_emb,
                                                   bsum, B_ * T_, G4H, E_, E_);
  for (int t = 0; t < T_; ++t) {
    hw_step<<<128, 128, 0, stream>>>(hT, WhT, hw, ctxAcc, denom);
    attn_slice<<<256, 256, 0, stream>>>(enc_bf, mask, Ke, v, hw, ctxAcc, denom);
    gate_step<<<256, 512, 0, stream>>>(t, WhhT, WihDT, g_emb, ctxAcc, denom,
                                       hT, hT2, cT, h_hist, out_h, out_c);
  }
  // logits = h_hist @ fcW + fcb  (4096 x 10000, K=512) -> f32
  gemm2<0, 0, 1><<<dim3(79, 32), 256, 0, stream>>>(h_hist, fcW, nullptr, (void*)out,
                                                   fcb, B_ * T_, V_, H_, H_);
}